// Round 1
// baseline (3410.115 us; speedup 1.0000x reference)
//
#include <hip/hip_runtime.h>
#include <cstdint>
#include <cstddef>

// Problem constants
#define BB 4
#define CC 512
#define TT 2048
#define DINNER 1024
#define DSTATE 16
#define NCH 16     // scan chunks
#define CHL 128    // chunk length = TT/NCH
#define MROWS (BB*TT)   // 8192
#define EPSF 1e-5f

__device__ __forceinline__ float silu_f(float x) { return x / (1.f + __expf(-x)); }
__device__ __forceinline__ float softplus_f(float x) { return x > 20.f ? x : log1pf(expf(x)); }

// ---------------------------------------------------------------------------
// Generic f32 GEMM: C[M,N] = A[M,K] @ W[N,K]^T   (W row-major N x K, ldw=K)
// BM=BN=64, BK=16, 256 threads, 4x4 micro-tile.
// EPI: 0 = plain store, 1 = +bias then softplus
// ACC: accumulate into C
// ---------------------------------------------------------------------------
template<int EPI, bool ACC>
__global__ __launch_bounds__(256) void gemm_k(const float* __restrict__ A, int lda,
                                              const float* __restrict__ W,
                                              float* __restrict__ C,
                                              int N, int K,
                                              const float* __restrict__ bias)
{
    __shared__ float As[16][68];
    __shared__ float Bs[16][68];
    const int tid = threadIdx.x;
    const int tx = tid & 15, ty = tid >> 4;
    const int m0 = blockIdx.y << 6, n0 = blockIdx.x << 6;
    const int lk4 = tid & 3, lrow = tid >> 2;
    float acc[4][4] = {};
    for (int k0 = 0; k0 < K; k0 += 16) {
        float4 av = *(const float4*)(A + (size_t)(m0 + lrow)*lda + k0 + lk4*4);
        float4 bv = *(const float4*)(W + (size_t)(n0 + lrow)*K  + k0 + lk4*4);
        As[lk4*4+0][lrow] = av.x; As[lk4*4+1][lrow] = av.y;
        As[lk4*4+2][lrow] = av.z; As[lk4*4+3][lrow] = av.w;
        Bs[lk4*4+0][lrow] = bv.x; Bs[lk4*4+1][lrow] = bv.y;
        Bs[lk4*4+2][lrow] = bv.z; Bs[lk4*4+3][lrow] = bv.w;
        __syncthreads();
        #pragma unroll
        for (int k = 0; k < 16; ++k) {
            const float4 a = *(const float4*)(&As[k][ty << 2]);
            const float4 b = *(const float4*)(&Bs[k][tx << 2]);
            float ar[4] = {a.x, a.y, a.z, a.w};
            float br[4] = {b.x, b.y, b.z, b.w};
            #pragma unroll
            for (int i = 0; i < 4; ++i)
                #pragma unroll
                for (int j = 0; j < 4; ++j)
                    acc[i][j] = fmaf(ar[i], br[j], acc[i][j]);
        }
        __syncthreads();
    }
    #pragma unroll
    for (int i = 0; i < 4; ++i) {
        int m = m0 + (ty << 2) + i;
        float* cp = C + (size_t)m*N + n0 + (tx << 2);
        float4 v = make_float4(acc[i][0], acc[i][1], acc[i][2], acc[i][3]);
        if constexpr (EPI == 1) {
            const float4 b4 = *(const float4*)(bias + n0 + (tx << 2));
            v.x = softplus_f(v.x + b4.x); v.y = softplus_f(v.y + b4.y);
            v.z = softplus_f(v.z + b4.z); v.w = softplus_f(v.w + b4.w);
        }
        if constexpr (ACC) {
            float4 o = *(const float4*)cp;
            v.x += o.x; v.y += o.y; v.z += o.z; v.w += o.w;
        }
        *(float4*)cp = v;
    }
}

// ---------------------------------------------------------------------------
// Front grouped conv: groups of 4 channels, kernel 3, pad 1. out += bias.
// ---------------------------------------------------------------------------
__global__ __launch_bounds__(256) void front_conv_k(const float* __restrict__ in,
                                                    const float* __restrict__ w,
                                                    const float* __restrict__ cb,
                                                    float* __restrict__ out)
{
    int idx = blockIdx.x*256 + threadIdx.x;     // (b*CC + c)*TT + t
    int t = idx & (TT-1);
    int bc = idx >> 11;
    int c = bc & (CC-1);
    const float* wr = w + c*12;
    const float* base = in + ((size_t)(bc & ~3) << 11) + t;  // channel group start
    float s = cb[c];
    #pragma unroll
    for (int i = 0; i < 4; ++i) {
        const float* ip = base + ((size_t)i << 11);
        float a = wr[i*3+1]*ip[0];
        if (t > 0)     a += wr[i*3+0]*ip[-1];
        if (t < TT-1)  a += wr[i*3+2]*ip[1];
        s += a;
    }
    out[idx] = s;
}

// GroupNorm stats: 16 (b,group) pairs, each over 128*2048 contiguous floats.
__global__ __launch_bounds__(256) void gn_stats_k(const float* __restrict__ x, float* __restrict__ red)
{
    int pair  = blockIdx.x >> 4;
    int slice = blockIdx.x & 15;
    const float* base = x + ((size_t)pair << 18);
    float s = 0.f, s2 = 0.f;
    int i0 = slice*16384 + threadIdx.x;
    int iend = slice*16384 + 16384;
    for (int i = i0; i < iend; i += 256) { float v = base[i]; s += v; s2 += v*v; }
    for (int off = 32; off > 0; off >>= 1) { s += __shfl_down(s, off, 64); s2 += __shfl_down(s2, off, 64); }
    __shared__ float sb[4][2];
    int wid = threadIdx.x >> 6, lane = threadIdx.x & 63;
    if (lane == 0) { sb[wid][0] = s; sb[wid][1] = s2; }
    __syncthreads();
    if (threadIdx.x == 0) {
        s  = sb[0][0]+sb[1][0]+sb[2][0]+sb[3][0];
        s2 = sb[0][1]+sb[1][1]+sb[2][1]+sb[3][1];
        atomicAdd(&red[pair*2+0], s);
        atomicAdd(&red[pair*2+1], s2);
    }
}

template<bool FIRST>
__global__ __launch_bounds__(256) void gn_apply_k(float* __restrict__ h, float* __restrict__ gsum,
    const float* __restrict__ red, const float* __restrict__ gw, const float* __restrict__ gb)
{
    int idx = blockIdx.x*256 + threadIdx.x;
    int c = (idx >> 11) & (CC-1);
    int pair = idx >> 18;
    const float inv = 1.f/262144.f;
    float mu = red[pair*2]*inv;
    float var = red[pair*2+1]*inv - mu*mu;
    float rs = rsqrtf(var + EPSF);
    float v = (h[idx]-mu)*rs*gw[c]+gb[c];
    float sv = v / (1.f + expf(-v));
    h[idx] = sv;
    gsum[idx] = FIRST ? sv : (gsum[idx] + sv);
}

// Batched tiled transpose: src (B,R,Cl) -> dst (B,Cl,R); optional mask zeroing on src-row index.
template<bool MASK>
__global__ void transpose_k(const float* __restrict__ src, float* __restrict__ dst,
                            int R, int Cl, const unsigned char* __restrict__ msk)
{
    __shared__ float tile[32][33];
    int b = blockIdx.z;
    int r0 = blockIdx.y << 5, c0 = blockIdx.x << 5;
    const float* s = src + (size_t)b*R*Cl;
    float* d = dst + (size_t)b*R*Cl;
    int tx = threadIdx.x, ty = threadIdx.y;
    #pragma unroll
    for (int j = 0; j < 32; j += 8) tile[ty+j][tx] = s[(size_t)(r0+ty+j)*Cl + c0+tx];
    __syncthreads();
    bool mz = false;
    if (MASK) mz = msk[(size_t)b*R + r0 + tx] != 0;
    #pragma unroll
    for (int j = 0; j < 32; j += 8) {
        float v = tile[tx][ty+j];
        if (MASK && mz) v = 0.f;
        d[(size_t)(c0+ty+j)*R + r0+tx] = v;
    }
}

// Depthwise causal conv (width 4, left pad 3) + bias + SiLU. Reads xh = xz[..., :1024].
__global__ __launch_bounds__(256) void mamba_conv_k(const float* __restrict__ xz,
    const float* __restrict__ w, const float* __restrict__ cb, float* __restrict__ xc)
{
    int idx = blockIdx.x*256 + threadIdx.x;     // (b*TT + t)*1024 + d
    int d = idx & (DINNER-1);
    int bt = idx >> 10;
    int t = bt & (TT-1);
    const float* wd = w + d*4;
    const float* src = xz + ((size_t)bt << 11) + d;
    float s = cb[d];
    #pragma unroll
    for (int k = 0; k < 4; ++k) {
        int dtt = k - 3;
        if (t + dtt >= 0) s += wd[k] * src[(ptrdiff_t)dtt << 11];
    }
    xc[idx] = silu_f(s);
}

// ---------------------------------------------------------------------------
// Chunked selective scan. Thread index for p1/p3: ((b*NCH + ch)*1024 + d).
// ---------------------------------------------------------------------------
__global__ __launch_bounds__(256) void scan_p1_k(const float* __restrict__ dt, const float* __restrict__ xc,
    const float* __restrict__ xdbl, const float* __restrict__ Alog,
    float* __restrict__ ch_h, float* __restrict__ ch_sd)
{
    int idx = blockIdx.x*256 + threadIdx.x;
    int d = idx & 1023;
    int bc = idx >> 10;
    int ch = bc & 15;
    int b = bc >> 4;
    float Ad[16];
    #pragma unroll
    for (int n = 0; n < 16; ++n) Ad[n] = -__expf(Alog[d*16+n]);
    float h[16];
    #pragma unroll
    for (int n = 0; n < 16; ++n) h[n] = 0.f;
    float sd = 0.f;
    size_t rbase = (size_t)(b*TT + ch*CHL);
    const float* dtp = dt + (rbase << 10) + d;
    const float* xcp = xc + (rbase << 10) + d;
    const float* xdp = xdbl + rbase*64 + 32;
    for (int tt = 0; tt < CHL; ++tt) {
        float dtv = dtp[(size_t)tt << 10];
        float u   = xcp[(size_t)tt << 10];
        sd += dtv;
        float du = dtv*u;
        const float* Bv = xdp + tt*64;
        #pragma unroll
        for (int n = 0; n < 16; ++n) h[n] = h[n]*__expf(dtv*Ad[n]) + du*Bv[n];
    }
    float* hp = ch_h + ((size_t)idx << 4);
    #pragma unroll
    for (int n = 0; n < 16; ++n) hp[n] = h[n];
    ch_sd[idx] = sd;
}

__global__ __launch_bounds__(256) void scan_p2_k(const float* __restrict__ Alog, const float* __restrict__ ch_h,
    const float* __restrict__ ch_sd, float* __restrict__ hinit)
{
    int idx = blockIdx.x*256 + threadIdx.x;     // b*16384 + d*16 + n
    int dn = idx & 16383;
    int b = idx >> 14;
    int d = dn >> 4;
    float A = -__expf(Alog[dn]);
    float h = 0.f;
    for (int ch = 0; ch < NCH; ++ch) {
        size_t o = ((size_t)((b*16 + ch)) << 14) + dn;
        hinit[o] = h;
        h = h*__expf(A*ch_sd[((b*16+ch) << 10) + d]) + ch_h[o];
    }
}

__global__ __launch_bounds__(256) void scan_p3_k(const float* __restrict__ dt, const float* __restrict__ xc,
    const float* __restrict__ xdbl, const float* __restrict__ Alog, const float* __restrict__ hinit,
    const float* __restrict__ xz, const float* __restrict__ Dp, float* __restrict__ y)
{
    int idx = blockIdx.x*256 + threadIdx.x;
    int d = idx & 1023;
    int bc = idx >> 10;
    int ch = bc & 15;
    int b = bc >> 4;
    float Ad[16];
    #pragma unroll
    for (int n = 0; n < 16; ++n) Ad[n] = -__expf(Alog[d*16+n]);
    float h[16];
    const float* hp = hinit + ((size_t)idx << 4);
    #pragma unroll
    for (int n = 0; n < 16; ++n) h[n] = hp[n];
    float Dv = Dp[d];
    size_t rbase = (size_t)(b*TT + ch*CHL);
    const float* dtp = dt + (rbase << 10) + d;
    const float* xcp = xc + (rbase << 10) + d;
    const float* xdp = xdbl + rbase*64;
    const float* zp  = xz + (rbase << 11) + 1024 + d;
    float* yp = y + (rbase << 10) + d;
    for (int tt = 0; tt < CHL; ++tt) {
        float dtv = dtp[(size_t)tt << 10];
        float u   = xcp[(size_t)tt << 10];
        float du = dtv*u;
        const float* Bv = xdp + tt*64 + 32;
        const float* Cv = xdp + tt*64 + 48;
        float acc = 0.f;
        #pragma unroll
        for (int n = 0; n < 16; ++n) {
            h[n] = h[n]*__expf(dtv*Ad[n]) + du*Bv[n];
            acc += h[n]*Cv[n];
        }
        float z = zp[(size_t)tt << 11];
        yp[(size_t)tt << 10] = (acc + u*Dv) * silu_f(z);
    }
}

// Fused gate-SiLU + LayerNorm over 1024 channels per (b,t) row.
__global__ __launch_bounds__(256) void gate_ln_k(const float* __restrict__ G1, const float* __restrict__ G2,
    const float* __restrict__ u, const float* __restrict__ mf,
    const float* __restrict__ lnw, const float* __restrict__ lnb, float* __restrict__ gt)
{
    int m = blockIdx.x;
    int tid = threadIdx.x;
    __shared__ float buf[1024];
    __shared__ float sb[4][2];
    __shared__ float stats[2];
    float s = 0.f, s2 = 0.f;
    #pragma unroll
    for (int c = tid; c < 1024; c += 256) {
        float g, comb;
        if (c < 512) { g = G1[(size_t)m*512 + c];       comb = u [(size_t)m*512 + c]; }
        else         { g = G2[(size_t)m*512 + c - 512]; comb = mf[(size_t)m*512 + c - 512]; }
        float v = (g / (1.f + expf(-g))) * comb;
        buf[c] = v;
        s += v; s2 += v*v;
    }
    for (int off = 32; off > 0; off >>= 1) { s += __shfl_down(s, off, 64); s2 += __shfl_down(s2, off, 64); }
    int wid = tid >> 6, lane = tid & 63;
    if (lane == 0) { sb[wid][0] = s; sb[wid][1] = s2; }
    __syncthreads();
    if (tid == 0) {
        float S  = sb[0][0]+sb[1][0]+sb[2][0]+sb[3][0];
        float S2 = sb[0][1]+sb[1][1]+sb[2][1]+sb[3][1];
        float mu = S*(1.f/1024.f);
        float var = S2*(1.f/1024.f) - mu*mu;
        stats[0] = mu; stats[1] = rsqrtf(var + EPSF);
    }
    __syncthreads();
    float mu = stats[0], rs = stats[1];
    #pragma unroll
    for (int c = tid; c < 1024; c += 256)
        gt[(size_t)m*1024 + c] = (buf[c]-mu)*rs*lnw[c] + lnb[c];
}

// ---------------------------------------------------------------------------
extern "C" void kernel_launch(void* const* d_in, const int* in_sizes, int n_in,
                              void* d_out, int out_size, void* d_ws, size_t ws_size,
                              hipStream_t stream)
{
    (void)in_sizes; (void)n_in; (void)out_size; (void)ws_size;
    const float* x        = (const float*)d_in[0];
    const float* conv_w   = (const float*)d_in[2];
    const float* conv_b   = (const float*)d_in[3];
    const float* gn_w     = (const float*)d_in[4];
    const float* gn_b     = (const float*)d_in[5];
    const float* in_projw = (const float*)d_in[6];
    const float* mconv_w  = (const float*)d_in[7];
    const float* mconv_b  = (const float*)d_in[8];
    const float* x_projw  = (const float*)d_in[9];
    const float* dt_projw = (const float*)d_in[10];
    const float* dt_projb = (const float*)d_in[11];
    const float* A_log    = (const float*)d_in[12];
    const float* Dp       = (const float*)d_in[13];
    const float* out_projw= (const float*)d_in[14];
    const float* gate_w   = (const float*)d_in[15];
    const float* ln_w     = (const float*)d_in[16];
    const float* ln_b     = (const float*)d_in[17];
    const float* proj_w   = (const float*)d_in[18];
    const unsigned char* msk = (const unsigned char*)d_in[19];
    float* out = (float*)d_out;
    float* ws  = (float*)d_ws;

    const size_t NEL = (size_t)BB*CC*TT;    // 4,194,304
    float* gsum = ws;
    float* hA   = gsum + NEL;
    float* hB   = hA + NEL;
    float* mf   = hB + NEL;                  // (8192,512)
    float* xz   = mf + NEL;                  // (8192,2048)
    float* xc   = xz + (size_t)MROWS*2048;   // (8192,1024)
    float* xdbl = xc + (size_t)MROWS*1024;   // (8192,64)
    float* dtb  = xdbl + (size_t)MROWS*64;   // (8192,1024)
    float* yb   = dtb + (size_t)MROWS*1024;  // (8192,1024)
    float* red  = yb + (size_t)MROWS*1024;   // 32 floats (+pad)
    float* ch_h = red + 64;                  // 65536*16
    float* ch_sd= ch_h + (size_t)65536*16;   // 65536
    float* hinit= ch_sd + 65536;             // 65536*16
    // Reused regions (free after the mamba loop):
    float* G1  = xz;
    float* G2  = xz + NEL;
    float* gt  = xc;
    float* gt2 = yb;
    float* u   = hB;   // gsum^T

    // ---- front conv/GN/SiLU stack (ping-pong hB/hA) ----
    const float* cur_in = x;
    float* pp[2] = {hB, hA};
    for (int i = 0; i < 4; ++i) {
        float* co = pp[i & 1];
        front_conv_k<<<16384, 256, 0, stream>>>(cur_in, conv_w + (size_t)i*CC*12, conv_b + i*CC, co);
        hipMemsetAsync(red, 0, 32*sizeof(float), stream);
        gn_stats_k<<<256, 256, 0, stream>>>(co, red);
        if (i == 0) gn_apply_k<true ><<<16384, 256, 0, stream>>>(co, gsum, red, gn_w + i*CC, gn_b + i*CC);
        else        gn_apply_k<false><<<16384, 256, 0, stream>>>(co, gsum, red, gn_w + i*CC, gn_b + i*CC);
        cur_in = co;
    }

    // u = gsum^T : (B,C,T) -> (B,T,C)
    transpose_k<false><<<dim3(64,16,4), dim3(32,8), 0, stream>>>(gsum, u, CC, TT, nullptr);

    // ---- 4 mamba blocks, all on u, accumulate into mf ----
    for (int i = 0; i < 4; ++i) {
        gemm_k<0,false><<<dim3(32,128), 256, 0, stream>>>(u, CC, in_projw + (size_t)i*2048*512, xz, 2048, 512, nullptr);
        mamba_conv_k<<<32768, 256, 0, stream>>>(xz, mconv_w + (size_t)i*DINNER*4, mconv_b + i*DINNER, xc);
        gemm_k<0,false><<<dim3(1,128), 256, 0, stream>>>(xc, 1024, x_projw + (size_t)i*64*1024, xdbl, 64, 1024, nullptr);
        gemm_k<1,false><<<dim3(16,128), 256, 0, stream>>>(xdbl, 64, dt_projw + (size_t)i*1024*32, dtb, 1024, 32, dt_projb + i*1024);
        scan_p1_k<<<256, 256, 0, stream>>>(dtb, xc, xdbl, A_log + (size_t)i*16384, ch_h, ch_sd);
        scan_p2_k<<<256, 256, 0, stream>>>(A_log + (size_t)i*16384, ch_h, ch_sd, hinit);
        scan_p3_k<<<256, 256, 0, stream>>>(dtb, xc, xdbl, A_log + (size_t)i*16384, hinit, xz, Dp + i*DINNER, yb);
        if (i == 0) gemm_k<0,false><<<dim3(8,128), 256, 0, stream>>>(yb, 1024, out_projw + (size_t)i*512*1024, mf, 512, 1024, nullptr);
        else        gemm_k<0,true ><<<dim3(8,128), 256, 0, stream>>>(yb, 1024, out_projw + (size_t)i*512*1024, mf, 512, 1024, nullptr);
    }

    // ---- gate conv (2 groups of 512, 1x1) + LN + proj + transpose/mask ----
    gemm_k<0,false><<<dim3(8,128), 256, 0, stream>>>(u,  CC, gate_w,           G1, 512, 512, nullptr);
    gemm_k<0,false><<<dim3(8,128), 256, 0, stream>>>(mf, CC, gate_w + 512*512, G2, 512, 512, nullptr);
    gate_ln_k<<<8192, 256, 0, stream>>>(G1, G2, u, mf, ln_w, ln_b, gt);
    gemm_k<0,false><<<dim3(8,128), 256, 0, stream>>>(gt, 1024, proj_w, gt2, 512, 1024, nullptr);
    transpose_k<true><<<dim3(16,64,4), dim3(32,8), 0, stream>>>(gt2, out, TT, CC, msk);
}

// Round 3
// 2536.365 us; speedup vs baseline: 1.3445x; 1.3445x over previous
//
#include <hip/hip_runtime.h>
#include <cstdint>
#include <cstddef>

// Problem constants
#define BB 4
#define CC 512
#define TT 2048
#define DINNER 1024
#define DSTATE 16
#define NCH 16     // scan chunks
#define CHL 128    // chunk length = TT/NCH
#define MROWS (BB*TT)   // 8192
#define EPSF 1e-5f

typedef __attribute__((ext_vector_type(8))) short short8;
typedef __attribute__((ext_vector_type(4))) float f32x4;

__device__ __forceinline__ float silu_f(float x) { return x / (1.f + __expf(-x)); }
__device__ __forceinline__ float softplus_f(float x) { return x > 20.f ? x : log1pf(expf(x)); }

__device__ __forceinline__ unsigned short f2bf(float x) {
    union { float f; unsigned u; } v; v.f = x;
    unsigned r = v.u + 0x7FFFu + ((v.u >> 16) & 1u);
    return (unsigned short)(r >> 16);
}
__device__ __forceinline__ float bf2f(unsigned short h) {
    union { unsigned u; float f; } v; v.u = ((unsigned)h) << 16;
    return v.f;
}

// ---------------------------------------------------------------------------
// Split-bf16 MFMA GEMM: C[M,N] = A[M,K] @ W[N,K]^T, f32 in/out, f32-grade
// accuracy via hi/lo bf16 decomposition (3 MFMA passes).
// BM=BN=128, BK=32, 256 threads = 4 waves (2x2), each wave 64x64.
// Requires: lda == K, M%128==0, N%128==0, K%32==0.
// ---------------------------------------------------------------------------
template<bool ACC>
__global__ __launch_bounds__(256, 2) void gemm_mfma_k(const float* __restrict__ A,
                                                      const float* __restrict__ W,
                                                      float* __restrict__ C,
                                                      int N, int K)
{
    // LDS tiles, row stride padded to 40 bf16 (80B) -> ~2-way (free) bank pattern
    __shared__ short Ah[128*40], Al[128*40], Bh[128*40], Bl[128*40];
    const int tid = threadIdx.x;
    const int m0 = blockIdx.y << 7, n0 = blockIdx.x << 7;
    const int srow = tid >> 1, skh = (tid & 1) << 4;   // staging: row, k-half
    const int wid = tid >> 6, lane = tid & 63;
    const int wr = wid >> 1, wc = wid & 1;             // wave (row,col) in 2x2
    const int l15 = lane & 15, l4 = lane >> 4;

    f32x4 acc[4][4] = {};

    const float* Ap = A + (size_t)(m0 + srow)*K + skh;
    const float* Wp = W + (size_t)(n0 + srow)*K + skh;
    const int sbase = srow*40 + skh;

    for (int k0 = 0; k0 < K; k0 += 32) {
        // ---- stage A and W tiles: f32 -> (hi,lo) bf16 pairs ----
        {
            f32x4 x0 = *(const f32x4*)(Ap + k0);
            f32x4 x1 = *(const f32x4*)(Ap + k0 + 4);
            f32x4 x2 = *(const f32x4*)(Ap + k0 + 8);
            f32x4 x3 = *(const f32x4*)(Ap + k0 + 12);
            float xs[16] = {x0[0],x0[1],x0[2],x0[3], x1[0],x1[1],x1[2],x1[3],
                            x2[0],x2[1],x2[2],x2[3], x3[0],x3[1],x3[2],x3[3]};
            unsigned hp[8], lp[8];
            #pragma unroll
            for (int p = 0; p < 8; ++p) {
                unsigned short h0 = f2bf(xs[2*p]),   h1 = f2bf(xs[2*p+1]);
                unsigned short g0 = f2bf(xs[2*p]   - bf2f(h0));
                unsigned short g1 = f2bf(xs[2*p+1] - bf2f(h1));
                hp[p] = (unsigned)h0 | ((unsigned)h1 << 16);
                lp[p] = (unsigned)g0 | ((unsigned)g1 << 16);
            }
            *(uint4*)&Ah[sbase]     = make_uint4(hp[0],hp[1],hp[2],hp[3]);
            *(uint4*)&Ah[sbase + 8] = make_uint4(hp[4],hp[5],hp[6],hp[7]);
            *(uint4*)&Al[sbase]     = make_uint4(lp[0],lp[1],lp[2],lp[3]);
            *(uint4*)&Al[sbase + 8] = make_uint4(lp[4],lp[5],lp[6],lp[7]);
        }
        {
            f32x4 x0 = *(const f32x4*)(Wp + k0);
            f32x4 x1 = *(const f32x4*)(Wp + k0 + 4);
            f32x4 x2 = *(const f32x4*)(Wp + k0 + 8);
            f32x4 x3 = *(const f32x4*)(Wp + k0 + 12);
            float xs[16] = {x0[0],x0[1],x0[2],x0[3], x1[0],x1[1],x1[2],x1[3],
                            x2[0],x2[1],x2[2],x2[3], x3[0],x3[1],x3[2],x3[3]};
            unsigned hp[8], lp[8];
            #pragma unroll
            for (int p = 0; p < 8; ++p) {
                unsigned short h0 = f2bf(xs[2*p]),   h1 = f2bf(xs[2*p+1]);
                unsigned short g0 = f2bf(xs[2*p]   - bf2f(h0));
                unsigned short g1 = f2bf(xs[2*p+1] - bf2f(h1));
                hp[p] = (unsigned)h0 | ((unsigned)h1 << 16);
                lp[p] = (unsigned)g0 | ((unsigned)g1 << 16);
            }
            *(uint4*)&Bh[sbase]     = make_uint4(hp[0],hp[1],hp[2],hp[3]);
            *(uint4*)&Bh[sbase + 8] = make_uint4(hp[4],hp[5],hp[6],hp[7]);
            *(uint4*)&Bl[sbase]     = make_uint4(lp[0],lp[1],lp[2],lp[3]);
            *(uint4*)&Bl[sbase + 8] = make_uint4(lp[4],lp[5],lp[6],lp[7]);
        }
        __syncthreads();

        // ---- fragments + 3-pass MFMA ----
        const int abase = (wr*64 + l15)*40 + l4*8;
        const int bbase = (wc*64 + l15)*40 + l4*8;
        short8 ah[4], al[4], bh[4], bl[4];
        #pragma unroll
        for (int i = 0; i < 4; ++i) {
            ah[i] = *(const short8*)&Ah[abase + i*640];
            al[i] = *(const short8*)&Al[abase + i*640];
            bh[i] = *(const short8*)&Bh[bbase + i*640];
            bl[i] = *(const short8*)&Bl[bbase + i*640];
        }
        #pragma unroll
        for (int i = 0; i < 4; ++i)
            #pragma unroll
            for (int j = 0; j < 4; ++j) {
                acc[i][j] = __builtin_amdgcn_mfma_f32_16x16x32_bf16(ah[i], bh[j], acc[i][j], 0, 0, 0);
                acc[i][j] = __builtin_amdgcn_mfma_f32_16x16x32_bf16(ah[i], bl[j], acc[i][j], 0, 0, 0);
                acc[i][j] = __builtin_amdgcn_mfma_f32_16x16x32_bf16(al[i], bh[j], acc[i][j], 0, 0, 0);
            }
        __syncthreads();
    }

    // ---- epilogue: C/D layout col=lane&15, row=(lane>>4)*4+reg ----
    #pragma unroll
    for (int i = 0; i < 4; ++i) {
        #pragma unroll
        for (int j = 0; j < 4; ++j) {
            const int col  = n0 + wc*64 + j*16 + l15;
            const int rowb = m0 + wr*64 + i*16 + l4*4;
            float* cp = C + (size_t)rowb*N + col;
            #pragma unroll
            for (int r = 0; r < 4; ++r) {
                float v = acc[i][j][r];
                if constexpr (ACC) v += cp[(size_t)r*N];
                cp[(size_t)r*N] = v;
            }
        }
    }
}

// ---------------------------------------------------------------------------
// Generic f32 GEMM (kept for small/sensitive GEMMs: x_proj N=64, dt_proj K=32)
// ---------------------------------------------------------------------------
template<int EPI, bool ACC>
__global__ __launch_bounds__(256) void gemm_k(const float* __restrict__ A, int lda,
                                              const float* __restrict__ W,
                                              float* __restrict__ C,
                                              int N, int K,
                                              const float* __restrict__ bias)
{
    __shared__ float As[16][68];
    __shared__ float Bs[16][68];
    const int tid = threadIdx.x;
    const int tx = tid & 15, ty = tid >> 4;
    const int m0 = blockIdx.y << 6, n0 = blockIdx.x << 6;
    const int lk4 = tid & 3, lrow = tid >> 2;
    float acc[4][4] = {};
    for (int k0 = 0; k0 < K; k0 += 16) {
        float4 av = *(const float4*)(A + (size_t)(m0 + lrow)*lda + k0 + lk4*4);
        float4 bv = *(const float4*)(W + (size_t)(n0 + lrow)*K  + k0 + lk4*4);
        As[lk4*4+0][lrow] = av.x; As[lk4*4+1][lrow] = av.y;
        As[lk4*4+2][lrow] = av.z; As[lk4*4+3][lrow] = av.w;
        Bs[lk4*4+0][lrow] = bv.x; Bs[lk4*4+1][lrow] = bv.y;
        Bs[lk4*4+2][lrow] = bv.z; Bs[lk4*4+3][lrow] = bv.w;
        __syncthreads();
        #pragma unroll
        for (int k = 0; k < 16; ++k) {
            const float4 a = *(const float4*)(&As[k][ty << 2]);
            const float4 b = *(const float4*)(&Bs[k][tx << 2]);
            float ar[4] = {a.x, a.y, a.z, a.w};
            float br[4] = {b.x, b.y, b.z, b.w};
            #pragma unroll
            for (int i = 0; i < 4; ++i)
                #pragma unroll
                for (int j = 0; j < 4; ++j)
                    acc[i][j] = fmaf(ar[i], br[j], acc[i][j]);
        }
        __syncthreads();
    }
    #pragma unroll
    for (int i = 0; i < 4; ++i) {
        int m = m0 + (ty << 2) + i;
        float* cp = C + (size_t)m*N + n0 + (tx << 2);
        float4 v = make_float4(acc[i][0], acc[i][1], acc[i][2], acc[i][3]);
        if constexpr (EPI == 1) {
            const float4 b4 = *(const float4*)(bias + n0 + (tx << 2));
            v.x = softplus_f(v.x + b4.x); v.y = softplus_f(v.y + b4.y);
            v.z = softplus_f(v.z + b4.z); v.w = softplus_f(v.w + b4.w);
        }
        if constexpr (ACC) {
            float4 o = *(const float4*)cp;
            v.x += o.x; v.y += o.y; v.z += o.z; v.w += o.w;
        }
        *(float4*)cp = v;
    }
}

// ---------------------------------------------------------------------------
// Front grouped conv: groups of 4 channels, kernel 3, pad 1. out += bias.
// ---------------------------------------------------------------------------
__global__ __launch_bounds__(256) void front_conv_k(const float* __restrict__ in,
                                                    const float* __restrict__ w,
                                                    const float* __restrict__ cb,
                                                    float* __restrict__ out)
{
    int idx = blockIdx.x*256 + threadIdx.x;     // (b*CC + c)*TT + t
    int t = idx & (TT-1);
    int bc = idx >> 11;
    int c = bc & (CC-1);
    const float* wr = w + c*12;
    const float* base = in + ((size_t)(bc & ~3) << 11) + t;  // channel group start
    float s = cb[c];
    #pragma unroll
    for (int i = 0; i < 4; ++i) {
        const float* ip = base + ((size_t)i << 11);
        float a = wr[i*3+1]*ip[0];
        if (t > 0)     a += wr[i*3+0]*ip[-1];
        if (t < TT-1)  a += wr[i*3+2]*ip[1];
        s += a;
    }
    out[idx] = s;
}

// GroupNorm stats: 16 (b,group) pairs, each over 128*2048 contiguous floats.
__global__ __launch_bounds__(256) void gn_stats_k(const float* __restrict__ x, float* __restrict__ red)
{
    int pair  = blockIdx.x >> 4;
    int slice = blockIdx.x & 15;
    const float* base = x + ((size_t)pair << 18);
    float s = 0.f, s2 = 0.f;
    int i0 = slice*16384 + threadIdx.x;
    int iend = slice*16384 + 16384;
    for (int i = i0; i < iend; i += 256) { float v = base[i]; s += v; s2 += v*v; }
    for (int off = 32; off > 0; off >>= 1) { s += __shfl_down(s, off, 64); s2 += __shfl_down(s2, off, 64); }
    __shared__ float sb[4][2];
    int wid = threadIdx.x >> 6, lane = threadIdx.x & 63;
    if (lane == 0) { sb[wid][0] = s; sb[wid][1] = s2; }
    __syncthreads();
    if (threadIdx.x == 0) {
        s  = sb[0][0]+sb[1][0]+sb[2][0]+sb[3][0];
        s2 = sb[0][1]+sb[1][1]+sb[2][1]+sb[3][1];
        atomicAdd(&red[pair*2+0], s);
        atomicAdd(&red[pair*2+1], s2);
    }
}

template<bool FIRST>
__global__ __launch_bounds__(256) void gn_apply_k(float* __restrict__ h, float* __restrict__ gsum,
    const float* __restrict__ red, const float* __restrict__ gw, const float* __restrict__ gb)
{
    int idx = blockIdx.x*256 + threadIdx.x;
    int c = (idx >> 11) & (CC-1);
    int pair = idx >> 18;
    const float inv = 1.f/262144.f;
    float mu = red[pair*2]*inv;
    float var = red[pair*2+1]*inv - mu*mu;
    float rs = rsqrtf(var + EPSF);
    float v = (h[idx]-mu)*rs*gw[c]+gb[c];
    float sv = v / (1.f + expf(-v));
    h[idx] = sv;
    gsum[idx] = FIRST ? sv : (gsum[idx] + sv);
}

// Batched tiled transpose: src (B,R,Cl) -> dst (B,Cl,R); optional mask zeroing on src-row index.
template<bool MASK>
__global__ void transpose_k(const float* __restrict__ src, float* __restrict__ dst,
                            int R, int Cl, const unsigned char* __restrict__ msk)
{
    __shared__ float tile[32][33];
    int b = blockIdx.z;
    int r0 = blockIdx.y << 5, c0 = blockIdx.x << 5;
    const float* s = src + (size_t)b*R*Cl;
    float* d = dst + (size_t)b*R*Cl;
    int tx = threadIdx.x, ty = threadIdx.y;
    #pragma unroll
    for (int j = 0; j < 32; j += 8) tile[ty+j][tx] = s[(size_t)(r0+ty+j)*Cl + c0+tx];
    __syncthreads();
    bool mz = false;
    if (MASK) mz = msk[(size_t)b*R + r0 + tx] != 0;
    #pragma unroll
    for (int j = 0; j < 32; j += 8) {
        float v = tile[tx][ty+j];
        if (MASK && mz) v = 0.f;
        d[(size_t)(c0+ty+j)*R + r0+tx] = v;
    }
}

// Depthwise causal conv (width 4, left pad 3) + bias + SiLU. Reads xh = xz[..., :1024].
__global__ __launch_bounds__(256) void mamba_conv_k(const float* __restrict__ xz,
    const float* __restrict__ w, const float* __restrict__ cb, float* __restrict__ xc)
{
    int idx = blockIdx.x*256 + threadIdx.x;     // (b*TT + t)*1024 + d
    int d = idx & (DINNER-1);
    int bt = idx >> 10;
    int t = bt & (TT-1);
    const float* wd = w + d*4;
    const float* src = xz + ((size_t)bt << 11) + d;
    float s = cb[d];
    #pragma unroll
    for (int k = 0; k < 4; ++k) {
        int dtt = k - 3;
        if (t + dtt >= 0) s += wd[k] * src[(ptrdiff_t)dtt << 11];
    }
    xc[idx] = silu_f(s);
}

// ---------------------------------------------------------------------------
// Chunked selective scan. Thread index for p1/p3: ((b*NCH + ch)*1024 + d).
// ---------------------------------------------------------------------------
__global__ __launch_bounds__(256) void scan_p1_k(const float* __restrict__ dt, const float* __restrict__ xc,
    const float* __restrict__ xdbl, const float* __restrict__ Alog,
    float* __restrict__ ch_h, float* __restrict__ ch_sd)
{
    int idx = blockIdx.x*256 + threadIdx.x;
    int d = idx & 1023;
    int bc = idx >> 10;
    int ch = bc & 15;
    int b = bc >> 4;
    float Ad[16];
    #pragma unroll
    for (int n = 0; n < 16; ++n) Ad[n] = -__expf(Alog[d*16+n]);
    float h[16];
    #pragma unroll
    for (int n = 0; n < 16; ++n) h[n] = 0.f;
    float sd = 0.f;
    size_t rbase = (size_t)(b*TT + ch*CHL);
    const float* dtp = dt + (rbase << 10) + d;
    const float* xcp = xc + (rbase << 10) + d;
    const float* xdp = xdbl + rbase*64 + 32;
    for (int tt = 0; tt < CHL; ++tt) {
        float dtv = dtp[(size_t)tt << 10];
        float u   = xcp[(size_t)tt << 10];
        sd += dtv;
        float du = dtv*u;
        const float* Bv = xdp + tt*64;
        #pragma unroll
        for (int n = 0; n < 16; ++n) h[n] = h[n]*__expf(dtv*Ad[n]) + du*Bv[n];
    }
    float* hp = ch_h + ((size_t)idx << 4);
    #pragma unroll
    for (int n = 0; n < 16; ++n) hp[n] = h[n];
    ch_sd[idx] = sd;
}

__global__ __launch_bounds__(256) void scan_p2_k(const float* __restrict__ Alog, const float* __restrict__ ch_h,
    const float* __restrict__ ch_sd, float* __restrict__ hinit)
{
    int idx = blockIdx.x*256 + threadIdx.x;     // b*16384 + d*16 + n
    int dn = idx & 16383;
    int b = idx >> 14;
    int d = dn >> 4;
    float A = -__expf(Alog[dn]);
    float h = 0.f;
    for (int ch = 0; ch < NCH; ++ch) {
        size_t o = ((size_t)((b*16 + ch)) << 14) + dn;
        hinit[o] = h;
        h = h*__expf(A*ch_sd[((b*16+ch) << 10) + d]) + ch_h[o];
    }
}

__global__ __launch_bounds__(256) void scan_p3_k(const float* __restrict__ dt, const float* __restrict__ xc,
    const float* __restrict__ xdbl, const float* __restrict__ Alog, const float* __restrict__ hinit,
    const float* __restrict__ xz, const float* __restrict__ Dp, float* __restrict__ y)
{
    int idx = blockIdx.x*256 + threadIdx.x;
    int d = idx & 1023;
    int bc = idx >> 10;
    int ch = bc & 15;
    int b = bc >> 4;
    float Ad[16];
    #pragma unroll
    for (int n = 0; n < 16; ++n) Ad[n] = -__expf(Alog[d*16+n]);
    float h[16];
    const float* hp = hinit + ((size_t)idx << 4);
    #pragma unroll
    for (int n = 0; n < 16; ++n) h[n] = hp[n];
    float Dv = Dp[d];
    size_t rbase = (size_t)(b*TT + ch*CHL);
    const float* dtp = dt + (rbase << 10) + d;
    const float* xcp = xc + (rbase << 10) + d;
    const float* xdp = xdbl + rbase*64;
    const float* zp  = xz + (rbase << 11) + 1024 + d;
    float* yp = y + (rbase << 10) + d;
    for (int tt = 0; tt < CHL; ++tt) {
        float dtv = dtp[(size_t)tt << 10];
        float u   = xcp[(size_t)tt << 10];
        float du = dtv*u;
        const float* Bv = xdp + tt*64 + 32;
        const float* Cv = xdp + tt*64 + 48;
        float acc = 0.f;
        #pragma unroll
        for (int n = 0; n < 16; ++n) {
            h[n] = h[n]*__expf(dtv*Ad[n]) + du*Bv[n];
            acc += h[n]*Cv[n];
        }
        float z = zp[(size_t)tt << 11];
        yp[(size_t)tt << 10] = (acc + u*Dv) * silu_f(z);
    }
}

// Fused gate-SiLU + LayerNorm over 1024 channels per (b,t) row.
__global__ __launch_bounds__(256) void gate_ln_k(const float* __restrict__ G1, const float* __restrict__ G2,
    const float* __restrict__ u, const float* __restrict__ mf,
    const float* __restrict__ lnw, const float* __restrict__ lnb, float* __restrict__ gt)
{
    int m = blockIdx.x;
    int tid = threadIdx.x;
    __shared__ float buf[1024];
    __shared__ float sb[4][2];
    __shared__ float stats[2];
    float s = 0.f, s2 = 0.f;
    #pragma unroll
    for (int c = tid; c < 1024; c += 256) {
        float g, comb;
        if (c < 512) { g = G1[(size_t)m*512 + c];       comb = u [(size_t)m*512 + c]; }
        else         { g = G2[(size_t)m*512 + c - 512]; comb = mf[(size_t)m*512 + c - 512]; }
        float v = (g / (1.f + expf(-g))) * comb;
        buf[c] = v;
        s += v; s2 += v*v;
    }
    for (int off = 32; off > 0; off >>= 1) { s += __shfl_down(s, off, 64); s2 += __shfl_down(s2, off, 64); }
    int wid = tid >> 6, lane = tid & 63;
    if (lane == 0) { sb[wid][0] = s; sb[wid][1] = s2; }
    __syncthreads();
    if (tid == 0) {
        float S  = sb[0][0]+sb[1][0]+sb[2][0]+sb[3][0];
        float S2 = sb[0][1]+sb[1][1]+sb[2][1]+sb[3][1];
        float mu = S*(1.f/1024.f);
        float var = S2*(1.f/1024.f) - mu*mu;
        stats[0] = mu; stats[1] = rsqrtf(var + EPSF);
    }
    __syncthreads();
    float mu = stats[0], rs = stats[1];
    #pragma unroll
    for (int c = tid; c < 1024; c += 256)
        gt[(size_t)m*1024 + c] = (buf[c]-mu)*rs*lnw[c] + lnb[c];
}

// ---------------------------------------------------------------------------
extern "C" void kernel_launch(void* const* d_in, const int* in_sizes, int n_in,
                              void* d_out, int out_size, void* d_ws, size_t ws_size,
                              hipStream_t stream)
{
    (void)in_sizes; (void)n_in; (void)out_size; (void)ws_size;
    const float* x        = (const float*)d_in[0];
    const float* conv_w   = (const float*)d_in[2];
    const float* conv_b   = (const float*)d_in[3];
    const float* gn_w     = (const float*)d_in[4];
    const float* gn_b     = (const float*)d_in[5];
    const float* in_projw = (const float*)d_in[6];
    const float* mconv_w  = (const float*)d_in[7];
    const float* mconv_b  = (const float*)d_in[8];
    const float* x_projw  = (const float*)d_in[9];
    const float* dt_projw = (const float*)d_in[10];
    const float* dt_projb = (const float*)d_in[11];
    const float* A_log    = (const float*)d_in[12];
    const float* Dp       = (const float*)d_in[13];
    const float* out_projw= (const float*)d_in[14];
    const float* gate_w   = (const float*)d_in[15];
    const float* ln_w     = (const float*)d_in[16];
    const float* ln_b     = (const float*)d_in[17];
    const float* proj_w   = (const float*)d_in[18];
    const unsigned char* msk = (const unsigned char*)d_in[19];
    float* out = (float*)d_out;
    float* ws  = (float*)d_ws;

    const size_t NEL = (size_t)BB*CC*TT;    // 4,194,304
    float* gsum = ws;
    float* hA   = gsum + NEL;
    float* hB   = hA + NEL;
    float* mf   = hB + NEL;                  // (8192,512)
    float* xz   = mf + NEL;                  // (8192,2048)
    float* xc   = xz + (size_t)MROWS*2048;   // (8192,1024)
    float* xdbl = xc + (size_t)MROWS*1024;   // (8192,64)
    float* dtb  = xdbl + (size_t)MROWS*64;   // (8192,1024)
    float* yb   = dtb + (size_t)MROWS*1024;  // (8192,1024)
    float* red  = yb + (size_t)MROWS*1024;   // 32 floats (+pad)
    float* ch_h = red + 64;                  // 65536*16
    float* ch_sd= ch_h + (size_t)65536*16;   // 65536
    float* hinit= ch_sd + 65536;             // 65536*16
    // Reused regions (free after the mamba loop):
    float* G1  = xz;
    float* G2  = xz + NEL;
    float* gt  = xc;
    float* gt2 = yb;
    float* u   = hB;   // gsum^T

    // ---- front conv/GN/SiLU stack (ping-pong hB/hA) ----
    const float* cur_in = x;
    float* pp[2] = {hB, hA};
    for (int i = 0; i < 4; ++i) {
        float* co = pp[i & 1];
        front_conv_k<<<16384, 256, 0, stream>>>(cur_in, conv_w + (size_t)i*CC*12, conv_b + i*CC, co);
        hipMemsetAsync(red, 0, 32*sizeof(float), stream);
        gn_stats_k<<<256, 256, 0, stream>>>(co, red);
        if (i == 0) gn_apply_k<true ><<<16384, 256, 0, stream>>>(co, gsum, red, gn_w + i*CC, gn_b + i*CC);
        else        gn_apply_k<false><<<16384, 256, 0, stream>>>(co, gsum, red, gn_w + i*CC, gn_b + i*CC);
        cur_in = co;
    }

    // u = gsum^T : (B,C,T) -> (B,T,C)
    transpose_k<false><<<dim3(64,16,4), dim3(32,8), 0, stream>>>(gsum, u, CC, TT, nullptr);

    // ---- 4 mamba blocks, all on u, accumulate into mf ----
    for (int i = 0; i < 4; ++i) {
        gemm_mfma_k<false><<<dim3(16,64), 256, 0, stream>>>(u, in_projw + (size_t)i*2048*512, xz, 2048, 512);
        mamba_conv_k<<<32768, 256, 0, stream>>>(xz, mconv_w + (size_t)i*DINNER*4, mconv_b + i*DINNER, xc);
        gemm_k<0,false><<<dim3(1,128), 256, 0, stream>>>(xc, 1024, x_projw + (size_t)i*64*1024, xdbl, 64, 1024, nullptr);
        gemm_k<1,false><<<dim3(16,128), 256, 0, stream>>>(xdbl, 64, dt_projw + (size_t)i*1024*32, dtb, 1024, 32, dt_projb + i*1024);
        scan_p1_k<<<256, 256, 0, stream>>>(dtb, xc, xdbl, A_log + (size_t)i*16384, ch_h, ch_sd);
        scan_p2_k<<<256, 256, 0, stream>>>(A_log + (size_t)i*16384, ch_h, ch_sd, hinit);
        scan_p3_k<<<256, 256, 0, stream>>>(dtb, xc, xdbl, A_log + (size_t)i*16384, hinit, xz, Dp + i*DINNER, yb);
        if (i == 0) gemm_mfma_k<false><<<dim3(4,64), 256, 0, stream>>>(yb, out_projw + (size_t)i*512*1024, mf, 512, 1024);
        else        gemm_mfma_k<true ><<<dim3(4,64), 256, 0, stream>>>(yb, out_projw + (size_t)i*512*1024, mf, 512, 1024);
    }

    // ---- gate conv (2 groups of 512, 1x1) + LN + proj + transpose/mask ----
    gemm_mfma_k<false><<<dim3(4,64), 256, 0, stream>>>(u,  gate_w,           G1, 512, 512);
    gemm_mfma_k<false><<<dim3(4,64), 256, 0, stream>>>(mf, gate_w + 512*512, G2, 512, 512);
    gate_ln_k<<<8192, 256, 0, stream>>>(G1, G2, u, mf, ln_w, ln_b, gt);
    gemm_mfma_k<false><<<dim3(4,64), 256, 0, stream>>>(gt, proj_w, gt2, 512, 1024);
    transpose_k<true><<<dim3(16,64,4), dim3(32,8), 0, stream>>>(gt2, out, TT, CC, msk);
}

// Round 6
// 2108.712 us; speedup vs baseline: 1.6172x; 1.2028x over previous
//
#include <hip/hip_runtime.h>
#include <cstdint>
#include <cstddef>

// Problem constants
#define BB 4
#define CC 512
#define TT 2048
#define DINNER 1024
#define DSTATE 16
#define NCH 64     // scan chunks (r3: 16 -> 64 for occupancy; scan was latency-bound at 10.5% occ)
#define NCHSH 6
#define CHL 32     // chunk length = TT/NCH
#define MROWS (BB*TT)   // 8192
#define EPSF 1e-5f

typedef __attribute__((ext_vector_type(8))) short short8;
typedef __attribute__((ext_vector_type(4))) float f32x4;

__device__ __forceinline__ float silu_f(float x) { return x / (1.f + __expf(-x)); }
__device__ __forceinline__ float softplus_f(float x) { return x > 20.f ? x : log1pf(expf(x)); }

__device__ __forceinline__ unsigned short f2bf(float x) {
    union { float f; unsigned u; } v; v.f = x;
    unsigned r = v.u + 0x7FFFu + ((v.u >> 16) & 1u);
    return (unsigned short)(r >> 16);
}
__device__ __forceinline__ float bf2f(unsigned short h) {
    union { unsigned u; float f; } v; v.u = ((unsigned)h) << 16;
    return v.f;
}

// ---------------------------------------------------------------------------
// Split-bf16 MFMA GEMM: C[M,N] = A[M,K] @ W[N,K]^T, f32 in/out, f32-grade
// accuracy via hi/lo bf16 decomposition (3 MFMA passes).
// BM=BN=128, BK=32, 256 threads = 4 waves (2x2), each wave 64x64.
// Requires: lda == K, M%128==0, N%128==0, K%32==0.
// ---------------------------------------------------------------------------
template<bool ACC>
__global__ __launch_bounds__(256, 2) void gemm_mfma_k(const float* __restrict__ A,
                                                      const float* __restrict__ W,
                                                      float* __restrict__ C,
                                                      int N, int K)
{
    // LDS tiles, row stride padded to 40 bf16 (80B) -> ~2-way (free) bank pattern
    __shared__ short Ah[128*40], Al[128*40], Bh[128*40], Bl[128*40];
    const int tid = threadIdx.x;
    const int m0 = blockIdx.y << 7, n0 = blockIdx.x << 7;
    const int srow = tid >> 1, skh = (tid & 1) << 4;   // staging: row, k-half
    const int wid = tid >> 6, lane = tid & 63;
    const int wr = wid >> 1, wc = wid & 1;             // wave (row,col) in 2x2
    const int l15 = lane & 15, l4 = lane >> 4;

    f32x4 acc[4][4] = {};

    const float* Ap = A + (size_t)(m0 + srow)*K + skh;
    const float* Wp = W + (size_t)(n0 + srow)*K + skh;
    const int sbase = srow*40 + skh;

    for (int k0 = 0; k0 < K; k0 += 32) {
        // ---- stage A and W tiles: f32 -> (hi,lo) bf16 pairs ----
        {
            f32x4 x0 = *(const f32x4*)(Ap + k0);
            f32x4 x1 = *(const f32x4*)(Ap + k0 + 4);
            f32x4 x2 = *(const f32x4*)(Ap + k0 + 8);
            f32x4 x3 = *(const f32x4*)(Ap + k0 + 12);
            float xs[16] = {x0[0],x0[1],x0[2],x0[3], x1[0],x1[1],x1[2],x1[3],
                            x2[0],x2[1],x2[2],x2[3], x3[0],x3[1],x3[2],x3[3]};
            unsigned hp[8], lp[8];
            #pragma unroll
            for (int p = 0; p < 8; ++p) {
                unsigned short h0 = f2bf(xs[2*p]),   h1 = f2bf(xs[2*p+1]);
                unsigned short g0 = f2bf(xs[2*p]   - bf2f(h0));
                unsigned short g1 = f2bf(xs[2*p+1] - bf2f(h1));
                hp[p] = (unsigned)h0 | ((unsigned)h1 << 16);
                lp[p] = (unsigned)g0 | ((unsigned)g1 << 16);
            }
            *(uint4*)&Ah[sbase]     = make_uint4(hp[0],hp[1],hp[2],hp[3]);
            *(uint4*)&Ah[sbase + 8] = make_uint4(hp[4],hp[5],hp[6],hp[7]);
            *(uint4*)&Al[sbase]     = make_uint4(lp[0],lp[1],lp[2],lp[3]);
            *(uint4*)&Al[sbase + 8] = make_uint4(lp[4],lp[5],lp[6],lp[7]);
        }
        {
            f32x4 x0 = *(const f32x4*)(Wp + k0);
            f32x4 x1 = *(const f32x4*)(Wp + k0 + 4);
            f32x4 x2 = *(const f32x4*)(Wp + k0 + 8);
            f32x4 x3 = *(const f32x4*)(Wp + k0 + 12);
            float xs[16] = {x0[0],x0[1],x0[2],x0[3], x1[0],x1[1],x1[2],x1[3],
                            x2[0],x2[1],x2[2],x2[3], x3[0],x3[1],x3[2],x3[3]};
            unsigned hp[8], lp[8];
            #pragma unroll
            for (int p = 0; p < 8; ++p) {
                unsigned short h0 = f2bf(xs[2*p]),   h1 = f2bf(xs[2*p+1]);
                unsigned short g0 = f2bf(xs[2*p]   - bf2f(h0));
                unsigned short g1 = f2bf(xs[2*p+1] - bf2f(h1));
                hp[p] = (unsigned)h0 | ((unsigned)h1 << 16);
                lp[p] = (unsigned)g0 | ((unsigned)g1 << 16);
            }
            *(uint4*)&Bh[sbase]     = make_uint4(hp[0],hp[1],hp[2],hp[3]);
            *(uint4*)&Bh[sbase + 8] = make_uint4(hp[4],hp[5],hp[6],hp[7]);
            *(uint4*)&Bl[sbase]     = make_uint4(lp[0],lp[1],lp[2],lp[3]);
            *(uint4*)&Bl[sbase + 8] = make_uint4(lp[4],lp[5],lp[6],lp[7]);
        }
        __syncthreads();

        // ---- fragments + 3-pass MFMA ----
        const int abase = (wr*64 + l15)*40 + l4*8;
        const int bbase = (wc*64 + l15)*40 + l4*8;
        short8 ah[4], al[4], bh[4], bl[4];
        #pragma unroll
        for (int i = 0; i < 4; ++i) {
            ah[i] = *(const short8*)&Ah[abase + i*640];
            al[i] = *(const short8*)&Al[abase + i*640];
            bh[i] = *(const short8*)&Bh[bbase + i*640];
            bl[i] = *(const short8*)&Bl[bbase + i*640];
        }
        #pragma unroll
        for (int i = 0; i < 4; ++i)
            #pragma unroll
            for (int j = 0; j < 4; ++j) {
                acc[i][j] = __builtin_amdgcn_mfma_f32_16x16x32_bf16(ah[i], bh[j], acc[i][j], 0, 0, 0);
                acc[i][j] = __builtin_amdgcn_mfma_f32_16x16x32_bf16(ah[i], bl[j], acc[i][j], 0, 0, 0);
                acc[i][j] = __builtin_amdgcn_mfma_f32_16x16x32_bf16(al[i], bh[j], acc[i][j], 0, 0, 0);
            }
        __syncthreads();
    }

    // ---- epilogue: C/D layout col=lane&15, row=(lane>>4)*4+reg ----
    #pragma unroll
    for (int i = 0; i < 4; ++i) {
        #pragma unroll
        for (int j = 0; j < 4; ++j) {
            const int col  = n0 + wc*64 + j*16 + l15;
            const int rowb = m0 + wr*64 + i*16 + l4*4;
            float* cp = C + (size_t)rowb*N + col;
            #pragma unroll
            for (int r = 0; r < 4; ++r) {
                float v = acc[i][j][r];
                if constexpr (ACC) v += cp[(size_t)r*N];
                cp[(size_t)r*N] = v;
            }
        }
    }
}

// ---------------------------------------------------------------------------
// Generic f32 GEMM (kept for small/sensitive GEMMs: x_proj N=64, dt_proj K=32)
// ---------------------------------------------------------------------------
template<int EPI, bool ACC>
__global__ __launch_bounds__(256) void gemm_k(const float* __restrict__ A, int lda,
                                              const float* __restrict__ W,
                                              float* __restrict__ C,
                                              int N, int K,
                                              const float* __restrict__ bias)
{
    __shared__ float As[16][68];
    __shared__ float Bs[16][68];
    const int tid = threadIdx.x;
    const int tx = tid & 15, ty = tid >> 4;
    const int m0 = blockIdx.y << 6, n0 = blockIdx.x << 6;
    const int lk4 = tid & 3, lrow = tid >> 2;
    float acc[4][4] = {};
    for (int k0 = 0; k0 < K; k0 += 16) {
        float4 av = *(const float4*)(A + (size_t)(m0 + lrow)*lda + k0 + lk4*4);
        float4 bv = *(const float4*)(W + (size_t)(n0 + lrow)*K  + k0 + lk4*4);
        As[lk4*4+0][lrow] = av.x; As[lk4*4+1][lrow] = av.y;
        As[lk4*4+2][lrow] = av.z; As[lk4*4+3][lrow] = av.w;
        Bs[lk4*4+0][lrow] = bv.x; Bs[lk4*4+1][lrow] = bv.y;
        Bs[lk4*4+2][lrow] = bv.z; Bs[lk4*4+3][lrow] = bv.w;
        __syncthreads();
        #pragma unroll
        for (int k = 0; k < 16; ++k) {
            const float4 a = *(const float4*)(&As[k][ty << 2]);
            const float4 b = *(const float4*)(&Bs[k][tx << 2]);
            float ar[4] = {a.x, a.y, a.z, a.w};
            float br[4] = {b.x, b.y, b.z, b.w};
            #pragma unroll
            for (int i = 0; i < 4; ++i)
                #pragma unroll
                for (int j = 0; j < 4; ++j)
                    acc[i][j] = fmaf(ar[i], br[j], acc[i][j]);
        }
        __syncthreads();
    }
    #pragma unroll
    for (int i = 0; i < 4; ++i) {
        int m = m0 + (ty << 2) + i;
        float* cp = C + (size_t)m*N + n0 + (tx << 2);
        float4 v = make_float4(acc[i][0], acc[i][1], acc[i][2], acc[i][3]);
        if constexpr (EPI == 1) {
            const float4 b4 = *(const float4*)(bias + n0 + (tx << 2));
            v.x = softplus_f(v.x + b4.x); v.y = softplus_f(v.y + b4.y);
            v.z = softplus_f(v.z + b4.z); v.w = softplus_f(v.w + b4.w);
        }
        if constexpr (ACC) {
            float4 o = *(const float4*)cp;
            v.x += o.x; v.y += o.y; v.z += o.z; v.w += o.w;
        }
        *(float4*)cp = v;
    }
}

// ---------------------------------------------------------------------------
// Front grouped conv: groups of 4 channels, kernel 3, pad 1. out += bias.
// ---------------------------------------------------------------------------
__global__ __launch_bounds__(256) void front_conv_k(const float* __restrict__ in,
                                                    const float* __restrict__ w,
                                                    const float* __restrict__ cb,
                                                    float* __restrict__ out)
{
    int idx = blockIdx.x*256 + threadIdx.x;     // (b*CC + c)*TT + t
    int t = idx & (TT-1);
    int bc = idx >> 11;
    int c = bc & (CC-1);
    const float* wr = w + c*12;
    const float* base = in + ((size_t)(bc & ~3) << 11) + t;  // channel group start
    float s = cb[c];
    #pragma unroll
    for (int i = 0; i < 4; ++i) {
        const float* ip = base + ((size_t)i << 11);
        float a = wr[i*3+1]*ip[0];
        if (t > 0)     a += wr[i*3+0]*ip[-1];
        if (t < TT-1)  a += wr[i*3+2]*ip[1];
        s += a;
    }
    out[idx] = s;
}

// GroupNorm stats: 16 (b,group) pairs, each over 128*2048 contiguous floats.
__global__ __launch_bounds__(256) void gn_stats_k(const float* __restrict__ x, float* __restrict__ red)
{
    int pair  = blockIdx.x >> 4;
    int slice = blockIdx.x & 15;
    const float* base = x + ((size_t)pair << 18);
    float s = 0.f, s2 = 0.f;
    int i0 = slice*16384 + threadIdx.x;
    int iend = slice*16384 + 16384;
    for (int i = i0; i < iend; i += 256) { float v = base[i]; s += v; s2 += v*v; }
    for (int off = 32; off > 0; off >>= 1) { s += __shfl_down(s, off, 64); s2 += __shfl_down(s2, off, 64); }
    __shared__ float sb[4][2];
    int wid = threadIdx.x >> 6, lane = threadIdx.x & 63;
    if (lane == 0) { sb[wid][0] = s; sb[wid][1] = s2; }
    __syncthreads();
    if (threadIdx.x == 0) {
        s  = sb[0][0]+sb[1][0]+sb[2][0]+sb[3][0];
        s2 = sb[0][1]+sb[1][1]+sb[2][1]+sb[3][1];
        atomicAdd(&red[pair*2+0], s);
        atomicAdd(&red[pair*2+1], s2);
    }
}

template<bool FIRST>
__global__ __launch_bounds__(256) void gn_apply_k(float* __restrict__ h, float* __restrict__ gsum,
    const float* __restrict__ red, const float* __restrict__ gw, const float* __restrict__ gb)
{
    int idx = blockIdx.x*256 + threadIdx.x;
    int c = (idx >> 11) & (CC-1);
    int pair = idx >> 18;
    const float inv = 1.f/262144.f;
    float mu = red[pair*2]*inv;
    float var = red[pair*2+1]*inv - mu*mu;
    float rs = rsqrtf(var + EPSF);
    float v = (h[idx]-mu)*rs*gw[c]+gb[c];
    float sv = v / (1.f + expf(-v));
    h[idx] = sv;
    gsum[idx] = FIRST ? sv : (gsum[idx] + sv);
}

// Batched tiled transpose: src (B,R,Cl) -> dst (B,Cl,R); optional mask zeroing on src-row index.
template<bool MASK>
__global__ void transpose_k(const float* __restrict__ src, float* __restrict__ dst,
                            int R, int Cl, const unsigned char* __restrict__ msk)
{
    __shared__ float tile[32][33];
    int b = blockIdx.z;
    int r0 = blockIdx.y << 5, c0 = blockIdx.x << 5;
    const float* s = src + (size_t)b*R*Cl;
    float* d = dst + (size_t)b*R*Cl;
    int tx = threadIdx.x, ty = threadIdx.y;
    #pragma unroll
    for (int j = 0; j < 32; j += 8) tile[ty+j][tx] = s[(size_t)(r0+ty+j)*Cl + c0+tx];
    __syncthreads();
    bool mz = false;
    if (MASK) mz = msk[(size_t)b*R + r0 + tx] != 0;
    #pragma unroll
    for (int j = 0; j < 32; j += 8) {
        float v = tile[tx][ty+j];
        if (MASK && mz) v = 0.f;
        d[(size_t)(c0+ty+j)*R + r0+tx] = v;
    }
}

// Depthwise causal conv (width 4, left pad 3) + bias + SiLU. Reads xh = xz[..., :1024].
__global__ __launch_bounds__(256) void mamba_conv_k(const float* __restrict__ xz,
    const float* __restrict__ w, const float* __restrict__ cb, float* __restrict__ xc)
{
    int idx = blockIdx.x*256 + threadIdx.x;     // (b*TT + t)*1024 + d
    int d = idx & (DINNER-1);
    int bt = idx >> 10;
    int t = bt & (TT-1);
    const float* wd = w + d*4;
    const float* src = xz + ((size_t)bt << 11) + d;
    float s = cb[d];
    #pragma unroll
    for (int k = 0; k < 4; ++k) {
        int dtt = k - 3;
        if (t + dtt >= 0) s += wd[k] * src[(ptrdiff_t)dtt << 11];
    }
    xc[idx] = silu_f(s);
}

// ---------------------------------------------------------------------------
// Chunked selective scan. Thread index for p1/p3: ((b*NCH + ch)*1024 + d).
// ---------------------------------------------------------------------------
__global__ __launch_bounds__(256) void scan_p1_k(const float* __restrict__ dt, const float* __restrict__ xc,
    const float* __restrict__ xdbl, const float* __restrict__ Alog,
    float* __restrict__ ch_h, float* __restrict__ ch_sd)
{
    int idx = blockIdx.x*256 + threadIdx.x;
    int d = idx & 1023;
    int bc = idx >> 10;
    int ch = bc & (NCH-1);
    int b = bc >> NCHSH;
    float Ad[16];
    #pragma unroll
    for (int n = 0; n < 16; ++n) Ad[n] = -__expf(Alog[d*16+n]);
    float h[16];
    #pragma unroll
    for (int n = 0; n < 16; ++n) h[n] = 0.f;
    float sd = 0.f;
    size_t rbase = (size_t)(b*TT + ch*CHL);
    const float* dtp = dt + (rbase << 10) + d;
    const float* xcp = xc + (rbase << 10) + d;
    const float* xdp = xdbl + rbase*64 + 32;
    for (int tt = 0; tt < CHL; ++tt) {
        float dtv = dtp[(size_t)tt << 10];
        float u   = xcp[(size_t)tt << 10];
        sd += dtv;
        float du = dtv*u;
        const float* Bv = xdp + tt*64;
        #pragma unroll
        for (int n = 0; n < 16; ++n) h[n] = h[n]*__expf(dtv*Ad[n]) + du*Bv[n];
    }
    float* hp = ch_h + ((size_t)idx << 4);
    #pragma unroll
    for (int n = 0; n < 16; ++n) hp[n] = h[n];
    ch_sd[idx] = sd;
}

__global__ __launch_bounds__(256) void scan_p2_k(const float* __restrict__ Alog, const float* __restrict__ ch_h,
    const float* __restrict__ ch_sd, float* __restrict__ hinit)
{
    int idx = blockIdx.x*256 + threadIdx.x;     // b*16384 + d*16 + n
    int dn = idx & 16383;
    int b = idx >> 14;
    int d = dn >> 4;
    float A = -__expf(Alog[dn]);
    float h = 0.f;
    for (int ch = 0; ch < NCH; ++ch) {
        size_t o = ((size_t)((b*NCH + ch)) << 14) + dn;
        hinit[o] = h;
        h = h*__expf(A*ch_sd[((b*NCH+ch) << 10) + d]) + ch_h[o];
    }
}

__global__ __launch_bounds__(256) void scan_p3_k(const float* __restrict__ dt, const float* __restrict__ xc,
    const float* __restrict__ xdbl, const float* __restrict__ Alog, const float* __restrict__ hinit,
    const float* __restrict__ xz, const float* __restrict__ Dp, float* __restrict__ y)
{
    int idx = blockIdx.x*256 + threadIdx.x;
    int d = idx & 1023;
    int bc = idx >> 10;
    int ch = bc & (NCH-1);
    int b = bc >> NCHSH;
    float Ad[16];
    #pragma unroll
    for (int n = 0; n < 16; ++n) Ad[n] = -__expf(Alog[d*16+n]);
    float h[16];
    const float* hp = hinit + ((size_t)idx << 4);
    #pragma unroll
    for (int n = 0; n < 16; ++n) h[n] = hp[n];
    float Dv = Dp[d];
    size_t rbase = (size_t)(b*TT + ch*CHL);
    const float* dtp = dt + (rbase << 10) + d;
    const float* xcp = xc + (rbase << 10) + d;
    const float* xdp = xdbl + rbase*64;
    const float* zp  = xz + (rbase << 11) + 1024 + d;
    float* yp = y + (rbase << 10) + d;
    for (int tt = 0; tt < CHL; ++tt) {
        float dtv = dtp[(size_t)tt << 10];
        float u   = xcp[(size_t)tt << 10];
        float du = dtv*u;
        const float* Bv = xdp + tt*64 + 32;
        const float* Cv = xdp + tt*64 + 48;
        float acc = 0.f;
        #pragma unroll
        for (int n = 0; n < 16; ++n) {
            h[n] = h[n]*__expf(dtv*Ad[n]) + du*Bv[n];
            acc += h[n]*Cv[n];
        }
        float z = zp[(size_t)tt << 11];
        yp[(size_t)tt << 10] = (acc + u*Dv) * silu_f(z);
    }
}

// Fused gate-SiLU + LayerNorm over 1024 channels per (b,t) row.
__global__ __launch_bounds__(256) void gate_ln_k(const float* __restrict__ G1, const float* __restrict__ G2,
    const float* __restrict__ u, const float* __restrict__ mf,
    const float* __restrict__ lnw, const float* __restrict__ lnb, float* __restrict__ gt)
{
    int m = blockIdx.x;
    int tid = threadIdx.x;
    __shared__ float buf[1024];
    __shared__ float sb[4][2];
    __shared__ float stats[2];
    float s = 0.f, s2 = 0.f;
    #pragma unroll
    for (int c = tid; c < 1024; c += 256) {
        float g, comb;
        if (c < 512) { g = G1[(size_t)m*512 + c];       comb = u [(size_t)m*512 + c]; }
        else         { g = G2[(size_t)m*512 + c - 512]; comb = mf[(size_t)m*512 + c - 512]; }
        float v = (g / (1.f + expf(-g))) * comb;
        buf[c] = v;
        s += v; s2 += v*v;
    }
    for (int off = 32; off > 0; off >>= 1) { s += __shfl_down(s, off, 64); s2 += __shfl_down(s2, off, 64); }
    int wid = tid >> 6, lane = tid & 63;
    if (lane == 0) { sb[wid][0] = s; sb[wid][1] = s2; }
    __syncthreads();
    if (tid == 0) {
        float S  = sb[0][0]+sb[1][0]+sb[2][0]+sb[3][0];
        float S2 = sb[0][1]+sb[1][1]+sb[2][1]+sb[3][1];
        float mu = S*(1.f/1024.f);
        float var = S2*(1.f/1024.f) - mu*mu;
        stats[0] = mu; stats[1] = rsqrtf(var + EPSF);
    }
    __syncthreads();
    float mu = stats[0], rs = stats[1];
    #pragma unroll
    for (int c = tid; c < 1024; c += 256)
        gt[(size_t)m*1024 + c] = (buf[c]-mu)*rs*lnw[c] + lnb[c];
}

// ---------------------------------------------------------------------------
extern "C" void kernel_launch(void* const* d_in, const int* in_sizes, int n_in,
                              void* d_out, int out_size, void* d_ws, size_t ws_size,
                              hipStream_t stream)
{
    (void)in_sizes; (void)n_in; (void)out_size; (void)ws_size;
    const float* x        = (const float*)d_in[0];
    const float* conv_w   = (const float*)d_in[2];
    const float* conv_b   = (const float*)d_in[3];
    const float* gn_w     = (const float*)d_in[4];
    const float* gn_b     = (const float*)d_in[5];
    const float* in_projw = (const float*)d_in[6];
    const float* mconv_w  = (const float*)d_in[7];
    const float* mconv_b  = (const float*)d_in[8];
    const float* x_projw  = (const float*)d_in[9];
    const float* dt_projw = (const float*)d_in[10];
    const float* dt_projb = (const float*)d_in[11];
    const float* A_log    = (const float*)d_in[12];
    const float* Dp       = (const float*)d_in[13];
    const float* out_projw= (const float*)d_in[14];
    const float* gate_w   = (const float*)d_in[15];
    const float* ln_w     = (const float*)d_in[16];
    const float* ln_b     = (const float*)d_in[17];
    const float* proj_w   = (const float*)d_in[18];
    const unsigned char* msk = (const unsigned char*)d_in[19];
    float* out = (float*)d_out;
    float* ws  = (float*)d_ws;

    const size_t NEL = (size_t)BB*CC*TT;        // 4,194,304
    const size_t NCHW = (size_t)BB*NCH*DINNER;  // 262,144 scan threads
    float* gsum = ws;                        // free after transpose -> reused as hinit
    float* hA   = gsum + NEL;                // front ping-pong; reused as ch_h in mamba loop
    float* hB   = hA + NEL;                  // reused as u (gsum^T)
    float* mf   = hB + NEL;                  // (8192,512)
    float* xz   = mf + NEL;                  // (8192,2048)
    float* xc   = xz + (size_t)MROWS*2048;   // (8192,1024)
    float* xdbl = xc + (size_t)MROWS*1024;   // (8192,64)
    float* dtb  = xdbl + (size_t)MROWS*64;   // (8192,1024)
    float* yb   = dtb + (size_t)MROWS*1024;  // (8192,1024)
    float* red  = yb + (size_t)MROWS*1024;   // 32 floats (+pad)
    float* ch_sd= red + 64;                  // NCHW floats
    // Aliased regions (dead originals):
    float* ch_h = hA;                        // NCHW*16 == NEL exactly (hA free after front stack)
    float* hinit= gsum;                      // NCHW*16 == NEL exactly (gsum free after transpose)
    float* G1  = xz;
    float* G2  = xz + NEL;
    float* gt  = xc;
    float* gt2 = yb;
    float* u   = hB;   // gsum^T

    // ---- front conv/GN/SiLU stack (ping-pong hB/hA) ----
    const float* cur_in = x;
    float* pp[2] = {hB, hA};
    for (int i = 0; i < 4; ++i) {
        float* co = pp[i & 1];
        front_conv_k<<<16384, 256, 0, stream>>>(cur_in, conv_w + (size_t)i*CC*12, conv_b + i*CC, co);
        hipMemsetAsync(red, 0, 32*sizeof(float), stream);
        gn_stats_k<<<256, 256, 0, stream>>>(co, red);
        if (i == 0) gn_apply_k<true ><<<16384, 256, 0, stream>>>(co, gsum, red, gn_w + i*CC, gn_b + i*CC);
        else        gn_apply_k<false><<<16384, 256, 0, stream>>>(co, gsum, red, gn_w + i*CC, gn_b + i*CC);
        cur_in = co;
    }

    // u = gsum^T : (B,C,T) -> (B,T,C)   (gsum dead afterwards -> becomes hinit)
    transpose_k<false><<<dim3(64,16,4), dim3(32,8), 0, stream>>>(gsum, u, CC, TT, nullptr);

    // ---- 4 mamba blocks, all on u, accumulate into mf ----
    for (int i = 0; i < 4; ++i) {
        gemm_mfma_k<false><<<dim3(16,64), 256, 0, stream>>>(u, in_projw + (size_t)i*2048*512, xz, 2048, 512);
        mamba_conv_k<<<32768, 256, 0, stream>>>(xz, mconv_w + (size_t)i*DINNER*4, mconv_b + i*DINNER, xc);
        gemm_k<0,false><<<dim3(1,128), 256, 0, stream>>>(xc, 1024, x_projw + (size_t)i*64*1024, xdbl, 64, 1024, nullptr);
        gemm_k<1,false><<<dim3(16,128), 256, 0, stream>>>(xdbl, 64, dt_projw + (size_t)i*1024*32, dtb, 1024, 32, dt_projb + i*1024);
        scan_p1_k<<<NCHW/256, 256, 0, stream>>>(dtb, xc, xdbl, A_log + (size_t)i*16384, ch_h, ch_sd);
        scan_p2_k<<<256, 256, 0, stream>>>(A_log + (size_t)i*16384, ch_h, ch_sd, hinit);
        scan_p3_k<<<NCHW/256, 256, 0, stream>>>(dtb, xc, xdbl, A_log + (size_t)i*16384, hinit, xz, Dp + i*DINNER, yb);
        if (i == 0) gemm_mfma_k<false><<<dim3(4,64), 256, 0, stream>>>(yb, out_projw + (size_t)i*512*1024, mf, 512, 1024);
        else        gemm_mfma_k<true ><<<dim3(4,64), 256, 0, stream>>>(yb, out_projw + (size_t)i*512*1024, mf, 512, 1024);
    }

    // ---- gate conv (2 groups of 512, 1x1) + LN + proj + transpose/mask ----
    gemm_mfma_k<false><<<dim3(4,64), 256, 0, stream>>>(u,  gate_w,           G1, 512, 512);
    gemm_mfma_k<false><<<dim3(4,64), 256, 0, stream>>>(mf, gate_w + 512*512, G2, 512, 512);
    gate_ln_k<<<8192, 256, 0, stream>>>(G1, G2, u, mf, ln_w, ln_b, gt);
    gemm_mfma_k<false><<<dim3(4,64), 256, 0, stream>>>(gt, proj_w, gt2, 512, 1024);
    transpose_k<true><<<dim3(16,64,4), dim3(32,8), 0, stream>>>(gt2, out, TT, CC, msk);
}

// Round 8
// 2094.104 us; speedup vs baseline: 1.6284x; 1.0070x over previous
//
#include <hip/hip_runtime.h>
#include <cstdint>
#include <cstddef>

// Problem constants
#define BB 4
#define CC 512
#define TT 2048
#define DINNER 1024
#define DSTATE 16
#define NCH 64     // scan chunks (r3: 16 -> 64 for occupancy; verified r6: -427us)
#define NCHSH 6
#define CHL 32     // chunk length = TT/NCH
#define MROWS (BB*TT)   // 8192
#define EPSF 1e-5f

typedef __attribute__((ext_vector_type(8))) short short8;
typedef __attribute__((ext_vector_type(4))) float f32x4;

__device__ __forceinline__ float silu_f(float x) { return x / (1.f + __expf(-x)); }
__device__ __forceinline__ float softplus_f(float x) { return x > 20.f ? x : log1pf(expf(x)); }

__device__ __forceinline__ unsigned short f2bf(float x) {
    union { float f; unsigned u; } v; v.f = x;
    unsigned r = v.u + 0x7FFFu + ((v.u >> 16) & 1u);
    return (unsigned short)(r >> 16);
}
__device__ __forceinline__ float bf2f(unsigned short h) {
    union { unsigned u; float f; } v; v.u = ((unsigned)h) << 16;
    return v.f;
}

// ---------------------------------------------------------------------------
// One-time f32 -> (hi,lo) bf16 split. n8 = element_count/8.
// ---------------------------------------------------------------------------
__global__ __launch_bounds__(256) void split_bf16_k(const float* __restrict__ in,
    unsigned short* __restrict__ hi, unsigned short* __restrict__ lo, int n8)
{
    for (int i = blockIdx.x*256 + threadIdx.x; i < n8; i += gridDim.x*256) {
        const f32x4* p = (const f32x4*)in + 2*(size_t)i;
        f32x4 a = p[0], b = p[1];
        float xs[8] = {a[0],a[1],a[2],a[3], b[0],b[1],b[2],b[3]};
        unsigned h[8], l[8];
        #pragma unroll
        for (int q = 0; q < 8; ++q) {
            unsigned short hh = f2bf(xs[q]);
            h[q] = hh;
            l[q] = f2bf(xs[q] - bf2f(hh));
        }
        ((uint4*)hi)[i] = make_uint4(h[0]|(h[1]<<16), h[2]|(h[3]<<16), h[4]|(h[5]<<16), h[6]|(h[7]<<16));
        ((uint4*)lo)[i] = make_uint4(l[0]|(l[1]<<16), l[2]|(l[3]<<16), l[4]|(l[5]<<16), l[6]|(l[7]<<16));
    }
}

// ---------------------------------------------------------------------------
// Pre-split bf16 3-pass MFMA GEMM: C[M,N] = A[M,K] @ W[N,K]^T (f32-grade).
// Inputs are pre-split (hi,lo) bf16 arrays; NO conversion in the K-loop.
// BM=128, BN=BNT (128 or 64), BK=32, 256 threads = 4 waves (2x2).
// Requires: M%128==0, N%BNT==0, K%32==0.
// ---------------------------------------------------------------------------
template<int BNT, bool ACC>
__global__ __launch_bounds__(256, 2) void gemm_bf16s_k(const unsigned short* __restrict__ Ahg,
    const unsigned short* __restrict__ Alg,
    const unsigned short* __restrict__ Whg, const unsigned short* __restrict__ Wlg,
    float* __restrict__ C, int N, int K)
{
    constexpr int NJ = BNT/32;
    constexpr int LDT = 40;   // row stride in shorts (80B, 16B-aligned)
    __shared__ short Ah[128*LDT], Al[128*LDT], Bh[BNT*LDT], Bl[BNT*LDT];
    const int tid = threadIdx.x;
    const int m0 = blockIdx.y << 7, n0 = blockIdx.x * BNT;
    const int srow = tid >> 2, scol = (tid & 3) << 3;
    const int wid = tid >> 6, lane = tid & 63;
    const int wr = wid >> 1, wc = wid & 1;
    const int l15 = lane & 15, l4 = lane >> 4;

    f32x4 acc[4][NJ] = {};

    for (int k0 = 0; k0 < K; k0 += 32) {
        size_t ga = (size_t)(m0 + srow)*K + k0 + scol;
        *(uint4*)&Ah[srow*LDT + scol] = *(const uint4*)(Ahg + ga);
        *(uint4*)&Al[srow*LDT + scol] = *(const uint4*)(Alg + ga);
        size_t ga2 = ga + (size_t)64*K;
        *(uint4*)&Ah[(srow+64)*LDT + scol] = *(const uint4*)(Ahg + ga2);
        *(uint4*)&Al[(srow+64)*LDT + scol] = *(const uint4*)(Alg + ga2);
        size_t gb = (size_t)(n0 + srow)*K + k0 + scol;
        *(uint4*)&Bh[srow*LDT + scol] = *(const uint4*)(Whg + gb);
        *(uint4*)&Bl[srow*LDT + scol] = *(const uint4*)(Wlg + gb);
        if constexpr (BNT == 128) {
            size_t gb2 = gb + (size_t)64*K;
            *(uint4*)&Bh[(srow+64)*LDT + scol] = *(const uint4*)(Whg + gb2);
            *(uint4*)&Bl[(srow+64)*LDT + scol] = *(const uint4*)(Wlg + gb2);
        }
        __syncthreads();

        short8 ah[4], al[4], bh[NJ], bl[NJ];
        const int ab = (wr*64 + l15)*LDT + l4*8;
        #pragma unroll
        for (int i = 0; i < 4; ++i) {
            ah[i] = *(const short8*)&Ah[ab + i*16*LDT];
            al[i] = *(const short8*)&Al[ab + i*16*LDT];
        }
        const int bb = (wc*(BNT/2) + l15)*LDT + l4*8;
        #pragma unroll
        for (int j = 0; j < NJ; ++j) {
            bh[j] = *(const short8*)&Bh[bb + j*16*LDT];
            bl[j] = *(const short8*)&Bl[bb + j*16*LDT];
        }
        #pragma unroll
        for (int i = 0; i < 4; ++i)
            #pragma unroll
            for (int j = 0; j < NJ; ++j) {
                acc[i][j] = __builtin_amdgcn_mfma_f32_16x16x32_bf16(ah[i], bh[j], acc[i][j], 0, 0, 0);
                acc[i][j] = __builtin_amdgcn_mfma_f32_16x16x32_bf16(ah[i], bl[j], acc[i][j], 0, 0, 0);
                acc[i][j] = __builtin_amdgcn_mfma_f32_16x16x32_bf16(al[i], bh[j], acc[i][j], 0, 0, 0);
            }
        __syncthreads();
    }

    #pragma unroll
    for (int i = 0; i < 4; ++i) {
        #pragma unroll
        for (int j = 0; j < NJ; ++j) {
            const int col  = n0 + wc*(BNT/2) + j*16 + l15;
            const int rowb = m0 + wr*64 + i*16 + l4*4;
            float* cp = C + (size_t)rowb*N + col;
            #pragma unroll
            for (int r = 0; r < 4; ++r) {
                float v = acc[i][j][r];
                if constexpr (ACC) v += cp[(size_t)r*N];
                cp[(size_t)r*N] = v;
            }
        }
    }
}

// ---------------------------------------------------------------------------
// r6 split-in-kernel MFMA GEMM (fallback path B when ws_size is too small).
// ---------------------------------------------------------------------------
template<bool ACC>
__global__ __launch_bounds__(256, 2) void gemm_mfma_k(const float* __restrict__ A,
                                                      const float* __restrict__ W,
                                                      float* __restrict__ C,
                                                      int N, int K)
{
    __shared__ short Ah[128*40], Al[128*40], Bh[128*40], Bl[128*40];
    const int tid = threadIdx.x;
    const int m0 = blockIdx.y << 7, n0 = blockIdx.x << 7;
    const int srow = tid >> 1, skh = (tid & 1) << 4;
    const int wid = tid >> 6, lane = tid & 63;
    const int wr = wid >> 1, wc = wid & 1;
    const int l15 = lane & 15, l4 = lane >> 4;

    f32x4 acc[4][4] = {};

    const float* Ap = A + (size_t)(m0 + srow)*K + skh;
    const float* Wp = W + (size_t)(n0 + srow)*K + skh;
    const int sbase = srow*40 + skh;

    for (int k0 = 0; k0 < K; k0 += 32) {
        {
            f32x4 x0 = *(const f32x4*)(Ap + k0);
            f32x4 x1 = *(const f32x4*)(Ap + k0 + 4);
            f32x4 x2 = *(const f32x4*)(Ap + k0 + 8);
            f32x4 x3 = *(const f32x4*)(Ap + k0 + 12);
            float xs[16] = {x0[0],x0[1],x0[2],x0[3], x1[0],x1[1],x1[2],x1[3],
                            x2[0],x2[1],x2[2],x2[3], x3[0],x3[1],x3[2],x3[3]};
            unsigned hp[8], lp[8];
            #pragma unroll
            for (int p = 0; p < 8; ++p) {
                unsigned short h0 = f2bf(xs[2*p]),   h1 = f2bf(xs[2*p+1]);
                unsigned short g0 = f2bf(xs[2*p]   - bf2f(h0));
                unsigned short g1 = f2bf(xs[2*p+1] - bf2f(h1));
                hp[p] = (unsigned)h0 | ((unsigned)h1 << 16);
                lp[p] = (unsigned)g0 | ((unsigned)g1 << 16);
            }
            *(uint4*)&Ah[sbase]     = make_uint4(hp[0],hp[1],hp[2],hp[3]);
            *(uint4*)&Ah[sbase + 8] = make_uint4(hp[4],hp[5],hp[6],hp[7]);
            *(uint4*)&Al[sbase]     = make_uint4(lp[0],lp[1],lp[2],lp[3]);
            *(uint4*)&Al[sbase + 8] = make_uint4(lp[4],lp[5],lp[6],lp[7]);
        }
        {
            f32x4 x0 = *(const f32x4*)(Wp + k0);
            f32x4 x1 = *(const f32x4*)(Wp + k0 + 4);
            f32x4 x2 = *(const f32x4*)(Wp + k0 + 8);
            f32x4 x3 = *(const f32x4*)(Wp + k0 + 12);
            float xs[16] = {x0[0],x0[1],x0[2],x0[3], x1[0],x1[1],x1[2],x1[3],
                            x2[0],x2[1],x2[2],x2[3], x3[0],x3[1],x3[2],x3[3]};
            unsigned hp[8], lp[8];
            #pragma unroll
            for (int p = 0; p < 8; ++p) {
                unsigned short h0 = f2bf(xs[2*p]),   h1 = f2bf(xs[2*p+1]);
                unsigned short g0 = f2bf(xs[2*p]   - bf2f(h0));
                unsigned short g1 = f2bf(xs[2*p+1] - bf2f(h1));
                hp[p] = (unsigned)h0 | ((unsigned)h1 << 16);
                lp[p] = (unsigned)g0 | ((unsigned)g1 << 16);
            }
            *(uint4*)&Bh[sbase]     = make_uint4(hp[0],hp[1],hp[2],hp[3]);
            *(uint4*)&Bh[sbase + 8] = make_uint4(hp[4],hp[5],hp[6],hp[7]);
            *(uint4*)&Bl[sbase]     = make_uint4(lp[0],lp[1],lp[2],lp[3]);
            *(uint4*)&Bl[sbase + 8] = make_uint4(lp[4],lp[5],lp[6],lp[7]);
        }
        __syncthreads();

        const int abase = (wr*64 + l15)*40 + l4*8;
        const int bbase = (wc*64 + l15)*40 + l4*8;
        short8 ah[4], al[4], bh[4], bl[4];
        #pragma unroll
        for (int i = 0; i < 4; ++i) {
            ah[i] = *(const short8*)&Ah[abase + i*640];
            al[i] = *(const short8*)&Al[abase + i*640];
            bh[i] = *(const short8*)&Bh[bbase + i*640];
            bl[i] = *(const short8*)&Bl[bbase + i*640];
        }
        #pragma unroll
        for (int i = 0; i < 4; ++i)
            #pragma unroll
            for (int j = 0; j < 4; ++j) {
                acc[i][j] = __builtin_amdgcn_mfma_f32_16x16x32_bf16(ah[i], bh[j], acc[i][j], 0, 0, 0);
                acc[i][j] = __builtin_amdgcn_mfma_f32_16x16x32_bf16(ah[i], bl[j], acc[i][j], 0, 0, 0);
                acc[i][j] = __builtin_amdgcn_mfma_f32_16x16x32_bf16(al[i], bh[j], acc[i][j], 0, 0, 0);
            }
        __syncthreads();
    }

    #pragma unroll
    for (int i = 0; i < 4; ++i) {
        #pragma unroll
        for (int j = 0; j < 4; ++j) {
            const int col  = n0 + wc*64 + j*16 + l15;
            const int rowb = m0 + wr*64 + i*16 + l4*4;
            float* cp = C + (size_t)rowb*N + col;
            #pragma unroll
            for (int r = 0; r < 4; ++r) {
                float v = acc[i][j][r];
                if constexpr (ACC) v += cp[(size_t)r*N];
                cp[(size_t)r*N] = v;
            }
        }
    }
}

// ---------------------------------------------------------------------------
// Generic f32 GEMM (small/sensitive GEMMs: x_proj N=64, dt_proj K=32)
// ---------------------------------------------------------------------------
template<int EPI, bool ACC>
__global__ __launch_bounds__(256) void gemm_k(const float* __restrict__ A, int lda,
                                              const float* __restrict__ W,
                                              float* __restrict__ C,
                                              int N, int K,
                                              const float* __restrict__ bias)
{
    __shared__ float As[16][68];
    __shared__ float Bs[16][68];
    const int tid = threadIdx.x;
    const int tx = tid & 15, ty = tid >> 4;
    const int m0 = blockIdx.y << 6, n0 = blockIdx.x << 6;
    const int lk4 = tid & 3, lrow = tid >> 2;
    float acc[4][4] = {};
    for (int k0 = 0; k0 < K; k0 += 16) {
        float4 av = *(const float4*)(A + (size_t)(m0 + lrow)*lda + k0 + lk4*4);
        float4 bv = *(const float4*)(W + (size_t)(n0 + lrow)*K  + k0 + lk4*4);
        As[lk4*4+0][lrow] = av.x; As[lk4*4+1][lrow] = av.y;
        As[lk4*4+2][lrow] = av.z; As[lk4*4+3][lrow] = av.w;
        Bs[lk4*4+0][lrow] = bv.x; Bs[lk4*4+1][lrow] = bv.y;
        Bs[lk4*4+2][lrow] = bv.z; Bs[lk4*4+3][lrow] = bv.w;
        __syncthreads();
        #pragma unroll
        for (int k = 0; k < 16; ++k) {
            const float4 a = *(const float4*)(&As[k][ty << 2]);
            const float4 b = *(const float4*)(&Bs[k][tx << 2]);
            float ar[4] = {a.x, a.y, a.z, a.w};
            float br[4] = {b.x, b.y, b.z, b.w};
            #pragma unroll
            for (int i = 0; i < 4; ++i)
                #pragma unroll
                for (int j = 0; j < 4; ++j)
                    acc[i][j] = fmaf(ar[i], br[j], acc[i][j]);
        }
        __syncthreads();
    }
    #pragma unroll
    for (int i = 0; i < 4; ++i) {
        int m = m0 + (ty << 2) + i;
        float* cp = C + (size_t)m*N + n0 + (tx << 2);
        float4 v = make_float4(acc[i][0], acc[i][1], acc[i][2], acc[i][3]);
        if constexpr (EPI == 1) {
            const float4 b4 = *(const float4*)(bias + n0 + (tx << 2));
            v.x = softplus_f(v.x + b4.x); v.y = softplus_f(v.y + b4.y);
            v.z = softplus_f(v.z + b4.z); v.w = softplus_f(v.w + b4.w);
        }
        if constexpr (ACC) {
            float4 o = *(const float4*)cp;
            v.x += o.x; v.y += o.y; v.z += o.z; v.w += o.w;
        }
        *(float4*)cp = v;
    }
}

// ---------------------------------------------------------------------------
// Front grouped conv: groups of 4 channels, kernel 3, pad 1. out += bias.
// ---------------------------------------------------------------------------
__global__ __launch_bounds__(256) void front_conv_k(const float* __restrict__ in,
                                                    const float* __restrict__ w,
                                                    const float* __restrict__ cb,
                                                    float* __restrict__ out)
{
    int idx = blockIdx.x*256 + threadIdx.x;
    int t = idx & (TT-1);
    int bc = idx >> 11;
    int c = bc & (CC-1);
    const float* wr = w + c*12;
    const float* base = in + ((size_t)(bc & ~3) << 11) + t;
    float s = cb[c];
    #pragma unroll
    for (int i = 0; i < 4; ++i) {
        const float* ip = base + ((size_t)i << 11);
        float a = wr[i*3+1]*ip[0];
        if (t > 0)     a += wr[i*3+0]*ip[-1];
        if (t < TT-1)  a += wr[i*3+2]*ip[1];
        s += a;
    }
    out[idx] = s;
}

// GroupNorm stats: 16 (b,group) pairs, each over 128*2048 contiguous floats.
__global__ __launch_bounds__(256) void gn_stats_k(const float* __restrict__ x, float* __restrict__ red)
{
    int pair  = blockIdx.x >> 4;
    int slice = blockIdx.x & 15;
    const float* base = x + ((size_t)pair << 18);
    float s = 0.f, s2 = 0.f;
    int i0 = slice*16384 + threadIdx.x;
    int iend = slice*16384 + 16384;
    for (int i = i0; i < iend; i += 256) { float v = base[i]; s += v; s2 += v*v; }
    for (int off = 32; off > 0; off >>= 1) { s += __shfl_down(s, off, 64); s2 += __shfl_down(s2, off, 64); }
    __shared__ float sb[4][2];
    int wid = threadIdx.x >> 6, lane = threadIdx.x & 63;
    if (lane == 0) { sb[wid][0] = s; sb[wid][1] = s2; }
    __syncthreads();
    if (threadIdx.x == 0) {
        s  = sb[0][0]+sb[1][0]+sb[2][0]+sb[3][0];
        s2 = sb[0][1]+sb[1][1]+sb[2][1]+sb[3][1];
        atomicAdd(&red[pair*2+0], s);
        atomicAdd(&red[pair*2+1], s2);
    }
}

template<bool FIRST>
__global__ __launch_bounds__(256) void gn_apply_k(float* __restrict__ h, float* __restrict__ gsum,
    const float* __restrict__ red, const float* __restrict__ gw, const float* __restrict__ gb)
{
    int idx = blockIdx.x*256 + threadIdx.x;
    int c = (idx >> 11) & (CC-1);
    int pair = idx >> 18;
    const float inv = 1.f/262144.f;
    float mu = red[pair*2]*inv;
    float var = red[pair*2+1]*inv - mu*mu;
    float rs = rsqrtf(var + EPSF);
    float v = (h[idx]-mu)*rs*gw[c]+gb[c];
    float sv = v / (1.f + expf(-v));
    h[idx] = sv;
    gsum[idx] = FIRST ? sv : (gsum[idx] + sv);
}

// Batched tiled transpose: src (B,R,Cl) -> dst (B,Cl,R); optional mask zeroing.
template<bool MASK>
__global__ void transpose_k(const float* __restrict__ src, float* __restrict__ dst,
                            int R, int Cl, const unsigned char* __restrict__ msk)
{
    __shared__ float tile[32][33];
    int b = blockIdx.z;
    int r0 = blockIdx.y << 5, c0 = blockIdx.x << 5;
    const float* s = src + (size_t)b*R*Cl;
    float* d = dst + (size_t)b*R*Cl;
    int tx = threadIdx.x, ty = threadIdx.y;
    #pragma unroll
    for (int j = 0; j < 32; j += 8) tile[ty+j][tx] = s[(size_t)(r0+ty+j)*Cl + c0+tx];
    __syncthreads();
    bool mz = false;
    if (MASK) mz = msk[(size_t)b*R + r0 + tx] != 0;
    #pragma unroll
    for (int j = 0; j < 32; j += 8) {
        float v = tile[tx][ty+j];
        if (MASK && mz) v = 0.f;
        d[(size_t)(c0+ty+j)*R + r0+tx] = v;
    }
}

// Depthwise causal conv (width 4, left pad 3) + bias + SiLU.
__global__ __launch_bounds__(256) void mamba_conv_k(const float* __restrict__ xz,
    const float* __restrict__ w, const float* __restrict__ cb, float* __restrict__ xc)
{
    int idx = blockIdx.x*256 + threadIdx.x;
    int d = idx & (DINNER-1);
    int bt = idx >> 10;
    int t = bt & (TT-1);
    const float* wd = w + d*4;
    const float* src = xz + ((size_t)bt << 11) + d;
    float s = cb[d];
    #pragma unroll
    for (int k = 0; k < 4; ++k) {
        int dtt = k - 3;
        if (t + dtt >= 0) s += wd[k] * src[(ptrdiff_t)dtt << 11];
    }
    xc[idx] = silu_f(s);
}

// ---------------------------------------------------------------------------
// Chunked selective scan.
// ---------------------------------------------------------------------------
__global__ __launch_bounds__(256) void scan_p1_k(const float* __restrict__ dt, const float* __restrict__ xc,
    const float* __restrict__ xdbl, const float* __restrict__ Alog,
    float* __restrict__ ch_h, float* __restrict__ ch_sd)
{
    int idx = blockIdx.x*256 + threadIdx.x;
    int d = idx & 1023;
    int bc = idx >> 10;
    int ch = bc & (NCH-1);
    int b = bc >> NCHSH;
    float Ad[16];
    #pragma unroll
    for (int n = 0; n < 16; ++n) Ad[n] = -__expf(Alog[d*16+n]);
    float h[16];
    #pragma unroll
    for (int n = 0; n < 16; ++n) h[n] = 0.f;
    float sd = 0.f;
    size_t rbase = (size_t)(b*TT + ch*CHL);
    const float* dtp = dt + (rbase << 10) + d;
    const float* xcp = xc + (rbase << 10) + d;
    const float* xdp = xdbl + rbase*64 + 32;
    for (int tt = 0; tt < CHL; ++tt) {
        float dtv = dtp[(size_t)tt << 10];
        float u   = xcp[(size_t)tt << 10];
        sd += dtv;
        float du = dtv*u;
        const float* Bv = xdp + tt*64;
        #pragma unroll
        for (int n = 0; n < 16; ++n) h[n] = h[n]*__expf(dtv*Ad[n]) + du*Bv[n];
    }
    float* hp = ch_h + ((size_t)idx << 4);
    #pragma unroll
    for (int n = 0; n < 16; ++n) hp[n] = h[n];
    ch_sd[idx] = sd;
}

__global__ __launch_bounds__(256) void scan_p2_k(const float* __restrict__ Alog, const float* __restrict__ ch_h,
    const float* __restrict__ ch_sd, float* __restrict__ hinit)
{
    int idx = blockIdx.x*256 + threadIdx.x;
    int dn = idx & 16383;
    int b = idx >> 14;
    int d = dn >> 4;
    float A = -__expf(Alog[dn]);
    float h = 0.f;
    for (int ch = 0; ch < NCH; ++ch) {
        size_t o = ((size_t)((b*NCH + ch)) << 14) + dn;
        hinit[o] = h;
        h = h*__expf(A*ch_sd[((b*NCH+ch) << 10) + d]) + ch_h[o];
    }
}

// BF=0: write f32 y. BF=1: write pre-split bf16 (yh, yl).
template<int BF>
__global__ __launch_bounds__(256) void scan_p3_k(const float* __restrict__ dt, const float* __restrict__ xc,
    const float* __restrict__ xdbl, const float* __restrict__ Alog, const float* __restrict__ hinit,
    const float* __restrict__ xz, const float* __restrict__ Dp, float* __restrict__ y,
    unsigned short* __restrict__ yh, unsigned short* __restrict__ yl)
{
    int idx = blockIdx.x*256 + threadIdx.x;
    int d = idx & 1023;
    int bc = idx >> 10;
    int ch = bc & (NCH-1);
    int b = bc >> NCHSH;
    float Ad[16];
    #pragma unroll
    for (int n = 0; n < 16; ++n) Ad[n] = -__expf(Alog[d*16+n]);
    float h[16];
    const float* hp = hinit + ((size_t)idx << 4);
    #pragma unroll
    for (int n = 0; n < 16; ++n) h[n] = hp[n];
    float Dv = Dp[d];
    size_t rbase = (size_t)(b*TT + ch*CHL);
    const float* dtp = dt + (rbase << 10) + d;
    const float* xcp = xc + (rbase << 10) + d;
    const float* xdp = xdbl + rbase*64;
    const float* zp  = xz + (rbase << 11) + 1024 + d;
    for (int tt = 0; tt < CHL; ++tt) {
        float dtv = dtp[(size_t)tt << 10];
        float u   = xcp[(size_t)tt << 10];
        float du = dtv*u;
        const float* Bv = xdp + tt*64 + 32;
        const float* Cv = xdp + tt*64 + 48;
        float acc = 0.f;
        #pragma unroll
        for (int n = 0; n < 16; ++n) {
            h[n] = h[n]*__expf(dtv*Ad[n]) + du*Bv[n];
            acc += h[n]*Cv[n];
        }
        float z = zp[(size_t)tt << 11];
        float yv = (acc + u*Dv) * silu_f(z);
        size_t o = ((rbase + tt) << 10) + d;
        if constexpr (BF == 0) {
            y[o] = yv;
        } else {
            unsigned short hh = f2bf(yv);
            yh[o] = hh;
            yl[o] = f2bf(yv - bf2f(hh));
        }
    }
}

// Fused gate-SiLU + LayerNorm. BF=0: write f32 gt; BF=1: write split bf16.
template<int BF>
__global__ __launch_bounds__(256) void gate_ln_k(const float* __restrict__ G1, const float* __restrict__ G2,
    const float* __restrict__ u, const float* __restrict__ mf,
    const float* __restrict__ lnw, const float* __restrict__ lnb,
    float* __restrict__ gt, unsigned short* __restrict__ gth, unsigned short* __restrict__ gtl)
{
    int m = blockIdx.x;
    int tid = threadIdx.x;
    __shared__ float buf[1024];
    __shared__ float sb[4][2];
    __shared__ float stats[2];
    float s = 0.f, s2 = 0.f;
    #pragma unroll
    for (int c = tid; c < 1024; c += 256) {
        float g, comb;
        if (c < 512) { g = G1[(size_t)m*512 + c];       comb = u [(size_t)m*512 + c]; }
        else         { g = G2[(size_t)m*512 + c - 512]; comb = mf[(size_t)m*512 + c - 512]; }
        float v = (g / (1.f + expf(-g))) * comb;
        buf[c] = v;
        s += v; s2 += v*v;
    }
    for (int off = 32; off > 0; off >>= 1) { s += __shfl_down(s, off, 64); s2 += __shfl_down(s2, off, 64); }
    int wid = tid >> 6, lane = tid & 63;
    if (lane == 0) { sb[wid][0] = s; sb[wid][1] = s2; }
    __syncthreads();
    if (tid == 0) {
        float S  = sb[0][0]+sb[1][0]+sb[2][0]+sb[3][0];
        float S2 = sb[0][1]+sb[1][1]+sb[2][1]+sb[3][1];
        float mu = S*(1.f/1024.f);
        float var = S2*(1.f/1024.f) - mu*mu;
        stats[0] = mu; stats[1] = rsqrtf(var + EPSF);
    }
    __syncthreads();
    float mu = stats[0], rs = stats[1];
    #pragma unroll
    for (int c = tid; c < 1024; c += 256) {
        float v = (buf[c]-mu)*rs*lnw[c] + lnb[c];
        size_t o = (size_t)m*1024 + c;
        if constexpr (BF == 0) {
            gt[o] = v;
        } else {
            unsigned short hh = f2bf(v);
            gth[o] = hh;
            gtl[o] = f2bf(v - bf2f(hh));
        }
    }
}

// ---------------------------------------------------------------------------
extern "C" void kernel_launch(void* const* d_in, const int* in_sizes, int n_in,
                              void* d_out, int out_size, void* d_ws, size_t ws_size,
                              hipStream_t stream)
{
    (void)in_sizes; (void)n_in; (void)out_size;
    const float* x        = (const float*)d_in[0];
    const float* conv_w   = (const float*)d_in[2];
    const float* conv_b   = (const float*)d_in[3];
    const float* gn_w     = (const float*)d_in[4];
    const float* gn_b     = (const float*)d_in[5];
    const float* in_projw = (const float*)d_in[6];
    const float* mconv_w  = (const float*)d_in[7];
    const float* mconv_b  = (const float*)d_in[8];
    const float* x_projw  = (const float*)d_in[9];
    const float* dt_projw = (const float*)d_in[10];
    const float* dt_projb = (const float*)d_in[11];
    const float* A_log    = (const float*)d_in[12];
    const float* Dp       = (const float*)d_in[13];
    const float* out_projw= (const float*)d_in[14];
    const float* gate_w   = (const float*)d_in[15];
    const float* ln_w     = (const float*)d_in[16];
    const float* ln_b     = (const float*)d_in[17];
    const float* proj_w   = (const float*)d_in[18];
    const unsigned char* msk = (const unsigned char*)d_in[19];
    float* out = (float*)d_out;
    float* ws  = (float*)d_ws;

    const size_t NEL = (size_t)BB*CC*TT;        // 4,194,304
    const size_t NCHW = (size_t)BB*NCH*DINNER;  // 262,144
    float* gsum = ws;
    float* hA   = gsum + NEL;
    float* hB   = hA + NEL;
    float* mf   = hB + NEL;
    float* xz   = mf + NEL;
    float* xc   = xz + (size_t)MROWS*2048;
    float* xdbl = xc + (size_t)MROWS*1024;
    float* dtb  = xdbl + (size_t)MROWS*64;
    float* yb   = dtb + (size_t)MROWS*1024;
    float* red  = yb + (size_t)MROWS*1024;
    float* ch_sd= red + 64;
    // Aliases
    float* ch_h = hA;
    float* hinit= gsum;
    float* G1  = xz;
    float* G2  = xz + NEL;
    float* u   = hB;

    // Path-A split-bf16 region (after ch_sd)
    const size_t IPW_E = (size_t)4*2048*512;   // 4,194,304
    const size_t OPW_E = (size_t)4*512*1024;   // 2,097,152
    const size_t GW_E  = (size_t)1024*512;     // 524,288
    const size_t PW_E  = (size_t)512*1024;     // 524,288
    unsigned short* ush = (unsigned short*)(ch_sd + NCHW);
    unsigned short* uhp  = ush;                 unsigned short* ulp  = uhp  + NEL;
    unsigned short* ipwh = ulp + NEL;           unsigned short* ipwl = ipwh + IPW_E;
    unsigned short* opwh = ipwl + IPW_E;        unsigned short* opwl = opwh + OPW_E;
    unsigned short* gwh  = opwl + OPW_E;        unsigned short* gwl  = gwh  + GW_E;
    unsigned short* pwh  = gwl + GW_E;          unsigned short* pwl  = pwh  + PW_E;
    size_t req = (size_t)((unsigned short*)(pwl + PW_E) - (unsigned short*)ws) * 2;
    const bool pathA = (ws_size >= req);
    // In-place bf16 aliases (dead f32 regions)
    unsigned short* ybh = (unsigned short*)yb;  unsigned short* ybl = ybh + (size_t)MROWS*1024;
    unsigned short* mfh = (unsigned short*)hA;  unsigned short* mfl = mfh + NEL;
    unsigned short* gth = (unsigned short*)yb;  unsigned short* gtl = gth + (size_t)MROWS*1024;
    float* gt2 = pathA ? xc : yb;   // proj output; path B keeps r6 placement (gt=xc, gt2=yb)
    float* gt  = xc;

    // ---- path A: split weights once ----
    if (pathA) {
        split_bf16_k<<<2048, 256, 0, stream>>>(in_projw,  ipwh, ipwl, (int)(IPW_E/8));
        split_bf16_k<<<1024, 256, 0, stream>>>(out_projw, opwh, opwl, (int)(OPW_E/8));
        split_bf16_k<<< 256, 256, 0, stream>>>(gate_w,    gwh,  gwl,  (int)(GW_E/8));
        split_bf16_k<<< 256, 256, 0, stream>>>(proj_w,    pwh,  pwl,  (int)(PW_E/8));
    }

    // ---- front conv/GN/SiLU stack (ping-pong hB/hA) ----
    const float* cur_in = x;
    float* pp[2] = {hB, hA};
    for (int i = 0; i < 4; ++i) {
        float* co = pp[i & 1];
        front_conv_k<<<16384, 256, 0, stream>>>(cur_in, conv_w + (size_t)i*CC*12, conv_b + i*CC, co);
        hipMemsetAsync(red, 0, 32*sizeof(float), stream);
        gn_stats_k<<<256, 256, 0, stream>>>(co, red);
        if (i == 0) gn_apply_k<true ><<<16384, 256, 0, stream>>>(co, gsum, red, gn_w + i*CC, gn_b + i*CC);
        else        gn_apply_k<false><<<16384, 256, 0, stream>>>(co, gsum, red, gn_w + i*CC, gn_b + i*CC);
        cur_in = co;
    }

    // u = gsum^T (gsum dead afterwards -> hinit)
    transpose_k<false><<<dim3(64,16,4), dim3(32,8), 0, stream>>>(gsum, u, CC, TT, nullptr);
    if (pathA) split_bf16_k<<<2048, 256, 0, stream>>>(u, uhp, ulp, (int)(NEL/8));

    // ---- 4 mamba blocks ----
    for (int i = 0; i < 4; ++i) {
        if (pathA)
            gemm_bf16s_k<128,false><<<dim3(16,64), 256, 0, stream>>>(uhp, ulp,
                ipwh + (size_t)i*2048*512, ipwl + (size_t)i*2048*512, xz, 2048, 512);
        else
            gemm_mfma_k<false><<<dim3(16,64), 256, 0, stream>>>(u, in_projw + (size_t)i*2048*512, xz, 2048, 512);
        mamba_conv_k<<<32768, 256, 0, stream>>>(xz, mconv_w + (size_t)i*DINNER*4, mconv_b + i*DINNER, xc);
        gemm_k<0,false><<<dim3(1,128), 256, 0, stream>>>(xc, 1024, x_projw + (size_t)i*64*1024, xdbl, 64, 1024, nullptr);
        gemm_k<1,false><<<dim3(16,128), 256, 0, stream>>>(xdbl, 64, dt_projw + (size_t)i*1024*32, dtb, 1024, 32, dt_projb + i*1024);
        scan_p1_k<<<NCHW/256, 256, 0, stream>>>(dtb, xc, xdbl, A_log + (size_t)i*16384, ch_h, ch_sd);
        scan_p2_k<<<256, 256, 0, stream>>>(A_log + (size_t)i*16384, ch_h, ch_sd, hinit);
        if (pathA) {
            scan_p3_k<1><<<NCHW/256, 256, 0, stream>>>(dtb, xc, xdbl, A_log + (size_t)i*16384, hinit, xz,
                                                       Dp + i*DINNER, nullptr, ybh, ybl);
            if (i == 0) gemm_bf16s_k<64,false><<<dim3(8,64), 256, 0, stream>>>(ybh, ybl,
                            opwh + (size_t)i*512*1024, opwl + (size_t)i*512*1024, mf, 512, 1024);
            else        gemm_bf16s_k<64,true ><<<dim3(8,64), 256, 0, stream>>>(ybh, ybl,
                            opwh + (size_t)i*512*1024, opwl + (size_t)i*512*1024, mf, 512, 1024);
        } else {
            scan_p3_k<0><<<NCHW/256, 256, 0, stream>>>(dtb, xc, xdbl, A_log + (size_t)i*16384, hinit, xz,
                                                       Dp + i*DINNER, yb, nullptr, nullptr);
            if (i == 0) gemm_mfma_k<false><<<dim3(4,64), 256, 0, stream>>>(yb, out_projw + (size_t)i*512*1024, mf, 512, 1024);
            else        gemm_mfma_k<true ><<<dim3(4,64), 256, 0, stream>>>(yb, out_projw + (size_t)i*512*1024, mf, 512, 1024);
        }
    }

    // ---- gate conv + LN + proj + transpose/mask ----
    if (pathA) {
        split_bf16_k<<<2048, 256, 0, stream>>>(mf, mfh, mfl, (int)(NEL/8));   // hA region is free now
        gemm_bf16s_k<64,false><<<dim3(8,64), 256, 0, stream>>>(uhp, ulp, gwh, gwl, G1, 512, 512);
        gemm_bf16s_k<64,false><<<dim3(8,64), 256, 0, stream>>>(mfh, mfl, gwh + (size_t)512*512, gwl + (size_t)512*512, G2, 512, 512);
        gate_ln_k<1><<<8192, 256, 0, stream>>>(G1, G2, u, mf, ln_w, ln_b, nullptr, gth, gtl);
        gemm_bf16s_k<64,false><<<dim3(8,64), 256, 0, stream>>>(gth, gtl, pwh, pwl, gt2, 512, 1024);
    } else {
        gemm_mfma_k<false><<<dim3(4,64), 256, 0, stream>>>(u,  gate_w,           G1, 512, 512);
        gemm_mfma_k<false><<<dim3(4,64), 256, 0, stream>>>(mf, gate_w + 512*512, G2, 512, 512);
        gate_ln_k<0><<<8192, 256, 0, stream>>>(G1, G2, u, mf, ln_w, ln_b, gt, nullptr, nullptr);
        gemm_mfma_k<false><<<dim3(4,64), 256, 0, stream>>>(gt, proj_w, gt2, 512, 1024);
    }
    transpose_k<true><<<dim3(16,64,4), dim3(32,8), 0, stream>>>(gt2, out, TT, CC, msk);
}

// Round 10
// 2025.307 us; speedup vs baseline: 1.6838x; 1.0340x over previous
//
#include <hip/hip_runtime.h>
#include <cstdint>
#include <cstddef>

// Problem constants
#define BB 4
#define CC 512
#define TT 2048
#define DINNER 1024
#define DSTATE 16
#define NCH 64     // scan chunks (r3: 16 -> 64 for occupancy; verified r6: -427us)
#define NCHSH 6
#define CHL 32     // chunk length = TT/NCH
#define MROWS (BB*TT)   // 8192
#define EPSF 1e-5f

typedef __attribute__((ext_vector_type(8))) short short8;
typedef __attribute__((ext_vector_type(4))) float f32x4;

__device__ __forceinline__ float silu_f(float x) { return x / (1.f + __expf(-x)); }
__device__ __forceinline__ float softplus_f(float x) { return x > 20.f ? x : log1pf(expf(x)); }

__device__ __forceinline__ unsigned short f2bf(float x) {
    union { float f; unsigned u; } v; v.f = x;
    unsigned r = v.u + 0x7FFFu + ((v.u >> 16) & 1u);
    return (unsigned short)(r >> 16);
}
__device__ __forceinline__ float bf2f(unsigned short h) {
    union { unsigned u; float f; } v; v.u = ((unsigned)h) << 16;
    return v.f;
}

// ---------------------------------------------------------------------------
// f32 -> (hi,lo) bf16 split. n8 = element_count/8.
// ---------------------------------------------------------------------------
__global__ __launch_bounds__(256) void split_bf16_k(const float* __restrict__ in,
    unsigned short* __restrict__ hi, unsigned short* __restrict__ lo, int n8)
{
    for (int i = blockIdx.x*256 + threadIdx.x; i < n8; i += gridDim.x*256) {
        const f32x4* p = (const f32x4*)in + 2*(size_t)i;
        f32x4 a = p[0], b = p[1];
        float xs[8] = {a[0],a[1],a[2],a[3], b[0],b[1],b[2],b[3]};
        unsigned h[8], l[8];
        #pragma unroll
        for (int q = 0; q < 8; ++q) {
            unsigned short hh = f2bf(xs[q]);
            h[q] = hh;
            l[q] = f2bf(xs[q] - bf2f(hh));
        }
        ((uint4*)hi)[i] = make_uint4(h[0]|(h[1]<<16), h[2]|(h[3]<<16), h[4]|(h[5]<<16), h[6]|(h[7]<<16));
        ((uint4*)lo)[i] = make_uint4(l[0]|(l[1]<<16), l[2]|(l[3]<<16), l[4]|(l[5]<<16), l[6]|(l[7]<<16));
    }
}

// Transpose (B,CC,TT) -> (B,TT,CC) emitting split (hi,lo) bf16.
__global__ void transpose_split_k(const float* __restrict__ src,
    unsigned short* __restrict__ dh, unsigned short* __restrict__ dl)
{
    __shared__ float tile[32][33];
    int b = blockIdx.z;
    int r0 = blockIdx.y << 5, c0 = blockIdx.x << 5;   // r over CC, c over TT
    const float* s = src + (size_t)b*CC*TT;
    int tx = threadIdx.x, ty = threadIdx.y;
    #pragma unroll
    for (int j = 0; j < 32; j += 8) tile[ty+j][tx] = s[(size_t)(r0+ty+j)*TT + c0+tx];
    __syncthreads();
    #pragma unroll
    for (int j = 0; j < 32; j += 8) {
        float v = tile[tx][ty+j];
        size_t o = (size_t)b*TT*CC + (size_t)(c0+ty+j)*CC + r0+tx;
        unsigned short hh = f2bf(v);
        dh[o] = hh;
        dl[o] = f2bf(v - bf2f(hh));
    }
}

// ---------------------------------------------------------------------------
// Pre-split bf16 3-pass MFMA GEMM: C[M,N] = A[M,K] @ W[N,K]^T (f32-grade).
// BM=128, BN=BNT (128 or 64), BK=32, 256 threads = 4 waves (2x2).
// Requires: M%128==0, N%BNT==0, K%32==0.
// ---------------------------------------------------------------------------
template<int BNT, bool ACC>
__global__ __launch_bounds__(256, 2) void gemm_bf16s_k(const unsigned short* __restrict__ Ahg,
    const unsigned short* __restrict__ Alg,
    const unsigned short* __restrict__ Whg, const unsigned short* __restrict__ Wlg,
    float* __restrict__ C, int N, int K)
{
    constexpr int NJ = BNT/32;
    constexpr int LDT = 40;   // row stride in shorts (80B, 16B-aligned)
    __shared__ short Ah[128*LDT], Al[128*LDT], Bh[BNT*LDT], Bl[BNT*LDT];
    const int tid = threadIdx.x;
    const int m0 = blockIdx.y << 7, n0 = blockIdx.x * BNT;
    const int srow = tid >> 2, scol = (tid & 3) << 3;
    const int wid = tid >> 6, lane = tid & 63;
    const int wr = wid >> 1, wc = wid & 1;
    const int l15 = lane & 15, l4 = lane >> 4;

    f32x4 acc[4][NJ] = {};

    for (int k0 = 0; k0 < K; k0 += 32) {
        size_t ga = (size_t)(m0 + srow)*K + k0 + scol;
        *(uint4*)&Ah[srow*LDT + scol] = *(const uint4*)(Ahg + ga);
        *(uint4*)&Al[srow*LDT + scol] = *(const uint4*)(Alg + ga);
        size_t ga2 = ga + (size_t)64*K;
        *(uint4*)&Ah[(srow+64)*LDT + scol] = *(const uint4*)(Ahg + ga2);
        *(uint4*)&Al[(srow+64)*LDT + scol] = *(const uint4*)(Alg + ga2);
        size_t gb = (size_t)(n0 + srow)*K + k0 + scol;
        *(uint4*)&Bh[srow*LDT + scol] = *(const uint4*)(Whg + gb);
        *(uint4*)&Bl[srow*LDT + scol] = *(const uint4*)(Wlg + gb);
        if constexpr (BNT == 128) {
            size_t gb2 = gb + (size_t)64*K;
            *(uint4*)&Bh[(srow+64)*LDT + scol] = *(const uint4*)(Whg + gb2);
            *(uint4*)&Bl[(srow+64)*LDT + scol] = *(const uint4*)(Wlg + gb2);
        }
        __syncthreads();

        short8 ah[4], al[4], bh[NJ], bl[NJ];
        const int ab = (wr*64 + l15)*LDT + l4*8;
        #pragma unroll
        for (int i = 0; i < 4; ++i) {
            ah[i] = *(const short8*)&Ah[ab + i*16*LDT];
            al[i] = *(const short8*)&Al[ab + i*16*LDT];
        }
        const int bb = (wc*(BNT/2) + l15)*LDT + l4*8;
        #pragma unroll
        for (int j = 0; j < NJ; ++j) {
            bh[j] = *(const short8*)&Bh[bb + j*16*LDT];
            bl[j] = *(const short8*)&Bl[bb + j*16*LDT];
        }
        #pragma unroll
        for (int i = 0; i < 4; ++i)
            #pragma unroll
            for (int j = 0; j < NJ; ++j) {
                acc[i][j] = __builtin_amdgcn_mfma_f32_16x16x32_bf16(ah[i], bh[j], acc[i][j], 0, 0, 0);
                acc[i][j] = __builtin_amdgcn_mfma_f32_16x16x32_bf16(ah[i], bl[j], acc[i][j], 0, 0, 0);
                acc[i][j] = __builtin_amdgcn_mfma_f32_16x16x32_bf16(al[i], bh[j], acc[i][j], 0, 0, 0);
            }
        __syncthreads();
    }

    #pragma unroll
    for (int i = 0; i < 4; ++i) {
        #pragma unroll
        for (int j = 0; j < NJ; ++j) {
            const int col  = n0 + wc*(BNT/2) + j*16 + l15;
            const int rowb = m0 + wr*64 + i*16 + l4*4;
            float* cp = C + (size_t)rowb*N + col;
            #pragma unroll
            for (int r = 0; r < 4; ++r) {
                float v = acc[i][j][r];
                if constexpr (ACC) v += cp[(size_t)r*N];
                cp[(size_t)r*N] = v;
            }
        }
    }
}

// ---------------------------------------------------------------------------
// r6 split-in-kernel MFMA GEMM (fallback path B when ws_size is too small).
// ---------------------------------------------------------------------------
template<bool ACC>
__global__ __launch_bounds__(256, 2) void gemm_mfma_k(const float* __restrict__ A,
                                                      const float* __restrict__ W,
                                                      float* __restrict__ C,
                                                      int N, int K)
{
    __shared__ short Ah[128*40], Al[128*40], Bh[128*40], Bl[128*40];
    const int tid = threadIdx.x;
    const int m0 = blockIdx.y << 7, n0 = blockIdx.x << 7;
    const int srow = tid >> 1, skh = (tid & 1) << 4;
    const int wid = tid >> 6, lane = tid & 63;
    const int wr = wid >> 1, wc = wid & 1;
    const int l15 = lane & 15, l4 = lane >> 4;

    f32x4 acc[4][4] = {};

    const float* Ap = A + (size_t)(m0 + srow)*K + skh;
    const float* Wp = W + (size_t)(n0 + srow)*K + skh;
    const int sbase = srow*40 + skh;

    for (int k0 = 0; k0 < K; k0 += 32) {
        {
            f32x4 x0 = *(const f32x4*)(Ap + k0);
            f32x4 x1 = *(const f32x4*)(Ap + k0 + 4);
            f32x4 x2 = *(const f32x4*)(Ap + k0 + 8);
            f32x4 x3 = *(const f32x4*)(Ap + k0 + 12);
            float xs[16] = {x0[0],x0[1],x0[2],x0[3], x1[0],x1[1],x1[2],x1[3],
                            x2[0],x2[1],x2[2],x2[3], x3[0],x3[1],x3[2],x3[3]};
            unsigned hp[8], lp[8];
            #pragma unroll
            for (int p = 0; p < 8; ++p) {
                unsigned short h0 = f2bf(xs[2*p]),   h1 = f2bf(xs[2*p+1]);
                unsigned short g0 = f2bf(xs[2*p]   - bf2f(h0));
                unsigned short g1 = f2bf(xs[2*p+1] - bf2f(h1));
                hp[p] = (unsigned)h0 | ((unsigned)h1 << 16);
                lp[p] = (unsigned)g0 | ((unsigned)g1 << 16);
            }
            *(uint4*)&Ah[sbase]     = make_uint4(hp[0],hp[1],hp[2],hp[3]);
            *(uint4*)&Ah[sbase + 8] = make_uint4(hp[4],hp[5],hp[6],hp[7]);
            *(uint4*)&Al[sbase]     = make_uint4(lp[0],lp[1],lp[2],lp[3]);
            *(uint4*)&Al[sbase + 8] = make_uint4(lp[4],lp[5],lp[6],lp[7]);
        }
        {
            f32x4 x0 = *(const f32x4*)(Wp + k0);
            f32x4 x1 = *(const f32x4*)(Wp + k0 + 4);
            f32x4 x2 = *(const f32x4*)(Wp + k0 + 8);
            f32x4 x3 = *(const f32x4*)(Wp + k0 + 12);
            float xs[16] = {x0[0],x0[1],x0[2],x0[3], x1[0],x1[1],x1[2],x1[3],
                            x2[0],x2[1],x2[2],x2[3], x3[0],x3[1],x3[2],x3[3]};
            unsigned hp[8], lp[8];
            #pragma unroll
            for (int p = 0; p < 8; ++p) {
                unsigned short h0 = f2bf(xs[2*p]),   h1 = f2bf(xs[2*p+1]);
                unsigned short g0 = f2bf(xs[2*p]   - bf2f(h0));
                unsigned short g1 = f2bf(xs[2*p+1] - bf2f(h1));
                hp[p] = (unsigned)h0 | ((unsigned)h1 << 16);
                lp[p] = (unsigned)g0 | ((unsigned)g1 << 16);
            }
            *(uint4*)&Bh[sbase]     = make_uint4(hp[0],hp[1],hp[2],hp[3]);
            *(uint4*)&Bh[sbase + 8] = make_uint4(hp[4],hp[5],hp[6],hp[7]);
            *(uint4*)&Bl[sbase]     = make_uint4(lp[0],lp[1],lp[2],lp[3]);
            *(uint4*)&Bl[sbase + 8] = make_uint4(lp[4],lp[5],lp[6],lp[7]);
        }
        __syncthreads();

        const int abase = (wr*64 + l15)*40 + l4*8;
        const int bbase = (wc*64 + l15)*40 + l4*8;
        short8 ah[4], al[4], bh[4], bl[4];
        #pragma unroll
        for (int i = 0; i < 4; ++i) {
            ah[i] = *(const short8*)&Ah[abase + i*640];
            al[i] = *(const short8*)&Al[abase + i*640];
            bh[i] = *(const short8*)&Bh[bbase + i*640];
            bl[i] = *(const short8*)&Bl[bbase + i*640];
        }
        #pragma unroll
        for (int i = 0; i < 4; ++i)
            #pragma unroll
            for (int j = 0; j < 4; ++j) {
                acc[i][j] = __builtin_amdgcn_mfma_f32_16x16x32_bf16(ah[i], bh[j], acc[i][j], 0, 0, 0);
                acc[i][j] = __builtin_amdgcn_mfma_f32_16x16x32_bf16(ah[i], bl[j], acc[i][j], 0, 0, 0);
                acc[i][j] = __builtin_amdgcn_mfma_f32_16x16x32_bf16(al[i], bh[j], acc[i][j], 0, 0, 0);
            }
        __syncthreads();
    }

    #pragma unroll
    for (int i = 0; i < 4; ++i) {
        #pragma unroll
        for (int j = 0; j < 4; ++j) {
            const int col  = n0 + wc*64 + j*16 + l15;
            const int rowb = m0 + wr*64 + i*16 + l4*4;
            float* cp = C + (size_t)rowb*N + col;
            #pragma unroll
            for (int r = 0; r < 4; ++r) {
                float v = acc[i][j][r];
                if constexpr (ACC) v += cp[(size_t)r*N];
                cp[(size_t)r*N] = v;
            }
        }
    }
}

// ---------------------------------------------------------------------------
// Generic f32 GEMM (small/sensitive GEMMs: x_proj N=64, dt_proj K=32)
// ---------------------------------------------------------------------------
template<int EPI, bool ACC>
__global__ __launch_bounds__(256) void gemm_k(const float* __restrict__ A, int lda,
                                              const float* __restrict__ W,
                                              float* __restrict__ C,
                                              int N, int K,
                                              const float* __restrict__ bias)
{
    __shared__ float As[16][68];
    __shared__ float Bs[16][68];
    const int tid = threadIdx.x;
    const int tx = tid & 15, ty = tid >> 4;
    const int m0 = blockIdx.y << 6, n0 = blockIdx.x << 6;
    const int lk4 = tid & 3, lrow = tid >> 2;
    float acc[4][4] = {};
    for (int k0 = 0; k0 < K; k0 += 16) {
        float4 av = *(const float4*)(A + (size_t)(m0 + lrow)*lda + k0 + lk4*4);
        float4 bv = *(const float4*)(W + (size_t)(n0 + lrow)*K  + k0 + lk4*4);
        As[lk4*4+0][lrow] = av.x; As[lk4*4+1][lrow] = av.y;
        As[lk4*4+2][lrow] = av.z; As[lk4*4+3][lrow] = av.w;
        Bs[lk4*4+0][lrow] = bv.x; Bs[lk4*4+1][lrow] = bv.y;
        Bs[lk4*4+2][lrow] = bv.z; Bs[lk4*4+3][lrow] = bv.w;
        __syncthreads();
        #pragma unroll
        for (int k = 0; k < 16; ++k) {
            const float4 a = *(const float4*)(&As[k][ty << 2]);
            const float4 b = *(const float4*)(&Bs[k][tx << 2]);
            float ar[4] = {a.x, a.y, a.z, a.w};
            float br[4] = {b.x, b.y, b.z, b.w};
            #pragma unroll
            for (int i = 0; i < 4; ++i)
                #pragma unroll
                for (int j = 0; j < 4; ++j)
                    acc[i][j] = fmaf(ar[i], br[j], acc[i][j]);
        }
        __syncthreads();
    }
    #pragma unroll
    for (int i = 0; i < 4; ++i) {
        int m = m0 + (ty << 2) + i;
        float* cp = C + (size_t)m*N + n0 + (tx << 2);
        float4 v = make_float4(acc[i][0], acc[i][1], acc[i][2], acc[i][3]);
        if constexpr (EPI == 1) {
            const float4 b4 = *(const float4*)(bias + n0 + (tx << 2));
            v.x = softplus_f(v.x + b4.x); v.y = softplus_f(v.y + b4.y);
            v.z = softplus_f(v.z + b4.z); v.w = softplus_f(v.w + b4.w);
        }
        if constexpr (ACC) {
            float4 o = *(const float4*)cp;
            v.x += o.x; v.y += o.y; v.z += o.z; v.w += o.w;
        }
        *(float4*)cp = v;
    }
}

// ---------------------------------------------------------------------------
// Front grouped conv: groups of 4 channels, kernel 3, pad 1. out += bias.
// ---------------------------------------------------------------------------
__global__ __launch_bounds__(256) void front_conv_k(const float* __restrict__ in,
                                                    const float* __restrict__ w,
                                                    const float* __restrict__ cb,
                                                    float* __restrict__ out)
{
    int idx = blockIdx.x*256 + threadIdx.x;
    int t = idx & (TT-1);
    int bc = idx >> 11;
    int c = bc & (CC-1);
    const float* wr = w + c*12;
    const float* base = in + ((size_t)(bc & ~3) << 11) + t;
    float s = cb[c];
    #pragma unroll
    for (int i = 0; i < 4; ++i) {
        const float* ip = base + ((size_t)i << 11);
        float a = wr[i*3+1]*ip[0];
        if (t > 0)     a += wr[i*3+0]*ip[-1];
        if (t < TT-1)  a += wr[i*3+2]*ip[1];
        s += a;
    }
    out[idx] = s;
}

// GroupNorm stats: 16 (b,group) pairs, each over 128*2048 contiguous floats.
__global__ __launch_bounds__(256) void gn_stats_k(const float* __restrict__ x, float* __restrict__ red)
{
    int pair  = blockIdx.x >> 4;
    int slice = blockIdx.x & 15;
    const float* base = x + ((size_t)pair << 18);
    float s = 0.f, s2 = 0.f;
    int i0 = slice*16384 + threadIdx.x;
    int iend = slice*16384 + 16384;
    for (int i = i0; i < iend; i += 256) { float v = base[i]; s += v; s2 += v*v; }
    for (int off = 32; off > 0; off >>= 1) { s += __shfl_down(s, off, 64); s2 += __shfl_down(s2, off, 64); }
    __shared__ float sb[4][2];
    int wid = threadIdx.x >> 6, lane = threadIdx.x & 63;
    if (lane == 0) { sb[wid][0] = s; sb[wid][1] = s2; }
    __syncthreads();
    if (threadIdx.x == 0) {
        s  = sb[0][0]+sb[1][0]+sb[2][0]+sb[3][0];
        s2 = sb[0][1]+sb[1][1]+sb[2][1]+sb[3][1];
        atomicAdd(&red[pair*2+0], s);
        atomicAdd(&red[pair*2+1], s2);
    }
}

template<bool FIRST>
__global__ __launch_bounds__(256) void gn_apply_k(float* __restrict__ h, float* __restrict__ gsum,
    const float* __restrict__ red, const float* __restrict__ gw, const float* __restrict__ gb)
{
    int idx = blockIdx.x*256 + threadIdx.x;
    int c = (idx >> 11) & (CC-1);
    int pair = idx >> 18;
    const float inv = 1.f/262144.f;
    float mu = red[pair*2]*inv;
    float var = red[pair*2+1]*inv - mu*mu;
    float rs = rsqrtf(var + EPSF);
    float v = (h[idx]-mu)*rs*gw[c]+gb[c];
    float sv = v / (1.f + expf(-v));
    h[idx] = sv;
    gsum[idx] = FIRST ? sv : (gsum[idx] + sv);
}

// Batched tiled transpose: src (B,R,Cl) -> dst (B,Cl,R); optional mask zeroing.
template<bool MASK>
__global__ void transpose_k(const float* __restrict__ src, float* __restrict__ dst,
                            int R, int Cl, const unsigned char* __restrict__ msk)
{
    __shared__ float tile[32][33];
    int b = blockIdx.z;
    int r0 = blockIdx.y << 5, c0 = blockIdx.x << 5;
    const float* s = src + (size_t)b*R*Cl;
    float* d = dst + (size_t)b*R*Cl;
    int tx = threadIdx.x, ty = threadIdx.y;
    #pragma unroll
    for (int j = 0; j < 32; j += 8) tile[ty+j][tx] = s[(size_t)(r0+ty+j)*Cl + c0+tx];
    __syncthreads();
    bool mz = false;
    if (MASK) mz = msk[(size_t)b*R + r0 + tx] != 0;
    #pragma unroll
    for (int j = 0; j < 32; j += 8) {
        float v = tile[tx][ty+j];
        if (MASK && mz) v = 0.f;
        d[(size_t)(c0+ty+j)*R + r0+tx] = v;
    }
}

// Depthwise causal conv (width 4, left pad 3) + bias + SiLU.
__global__ __launch_bounds__(256) void mamba_conv_k(const float* __restrict__ xz,
    const float* __restrict__ w, const float* __restrict__ cb, float* __restrict__ xc)
{
    int idx = blockIdx.x*256 + threadIdx.x;
    int d = idx & (DINNER-1);
    int bt = idx >> 10;
    int t = bt & (TT-1);
    const float* wd = w + d*4;
    const float* src = xz + ((size_t)bt << 11) + d;
    float s = cb[d];
    #pragma unroll
    for (int k = 0; k < 4; ++k) {
        int dtt = k - 3;
        if (t + dtt >= 0) s += wd[k] * src[(ptrdiff_t)dtt << 11];
    }
    xc[idx] = silu_f(s);
}

// ---------------------------------------------------------------------------
// Chunked selective scan.
// ---------------------------------------------------------------------------
__global__ __launch_bounds__(256) void scan_p1_k(const float* __restrict__ dt, const float* __restrict__ xc,
    const float* __restrict__ xdbl, const float* __restrict__ Alog,
    float* __restrict__ ch_h, float* __restrict__ ch_sd)
{
    int idx = blockIdx.x*256 + threadIdx.x;
    int d = idx & 1023;
    int bc = idx >> 10;
    int ch = bc & (NCH-1);
    int b = bc >> NCHSH;
    float Ad[16];
    #pragma unroll
    for (int n = 0; n < 16; ++n) Ad[n] = -__expf(Alog[d*16+n]);
    float h[16];
    #pragma unroll
    for (int n = 0; n < 16; ++n) h[n] = 0.f;
    float sd = 0.f;
    size_t rbase = (size_t)(b*TT + ch*CHL);
    const float* dtp = dt + (rbase << 10) + d;
    const float* xcp = xc + (rbase << 10) + d;
    const float* xdp = xdbl + rbase*64 + 32;
    for (int tt = 0; tt < CHL; ++tt) {
        float dtv = dtp[(size_t)tt << 10];
        float u   = xcp[(size_t)tt << 10];
        sd += dtv;
        float du = dtv*u;
        const float* Bv = xdp + tt*64;
        #pragma unroll
        for (int n = 0; n < 16; ++n) h[n] = h[n]*__expf(dtv*Ad[n]) + du*Bv[n];
    }
    float* hp = ch_h + ((size_t)idx << 4);
    #pragma unroll
    for (int n = 0; n < 16; ++n) hp[n] = h[n];
    ch_sd[idx] = sd;
}

__global__ __launch_bounds__(256) void scan_p2_k(const float* __restrict__ Alog, const float* __restrict__ ch_h,
    const float* __restrict__ ch_sd, float* __restrict__ hinit)
{
    int idx = blockIdx.x*256 + threadIdx.x;
    int dn = idx & 16383;
    int b = idx >> 14;
    int d = dn >> 4;
    float A = -__expf(Alog[dn]);
    float h = 0.f;
    for (int ch = 0; ch < NCH; ++ch) {
        size_t o = ((size_t)((b*NCH + ch)) << 14) + dn;
        hinit[o] = h;
        h = h*__expf(A*ch_sd[((b*NCH+ch) << 10) + d]) + ch_h[o];
    }
}

// BF=0: write f32 y. BF=1: write pre-split bf16 (yh, yl).
template<int BF>
__global__ __launch_bounds__(256) void scan_p3_k(const float* __restrict__ dt, const float* __restrict__ xc,
    const float* __restrict__ xdbl, const float* __restrict__ Alog, const float* __restrict__ hinit,
    const float* __restrict__ xz, const float* __restrict__ Dp, float* __restrict__ y,
    unsigned short* __restrict__ yh, unsigned short* __restrict__ yl)
{
    int idx = blockIdx.x*256 + threadIdx.x;
    int d = idx & 1023;
    int bc = idx >> 10;
    int ch = bc & (NCH-1);
    int b = bc >> NCHSH;
    float Ad[16];
    #pragma unroll
    for (int n = 0; n < 16; ++n) Ad[n] = -__expf(Alog[d*16+n]);
    float h[16];
    const float* hp = hinit + ((size_t)idx << 4);
    #pragma unroll
    for (int n = 0; n < 16; ++n) h[n] = hp[n];
    float Dv = Dp[d];
    size_t rbase = (size_t)(b*TT + ch*CHL);
    const float* dtp = dt + (rbase << 10) + d;
    const float* xcp = xc + (rbase << 10) + d;
    const float* xdp = xdbl + rbase*64;
    const float* zp  = xz + (rbase << 11) + 1024 + d;
    for (int tt = 0; tt < CHL; ++tt) {
        float dtv = dtp[(size_t)tt << 10];
        float u   = xcp[(size_t)tt << 10];
        float du = dtv*u;
        const float* Bv = xdp + tt*64 + 32;
        const float* Cv = xdp + tt*64 + 48;
        float acc = 0.f;
        #pragma unroll
        for (int n = 0; n < 16; ++n) {
            h[n] = h[n]*__expf(dtv*Ad[n]) + du*Bv[n];
            acc += h[n]*Cv[n];
        }
        float z = zp[(size_t)tt << 11];
        float yv = (acc + u*Dv) * silu_f(z);
        size_t o = ((rbase + tt) << 10) + d;
        if constexpr (BF == 0) {
            y[o] = yv;
        } else {
            unsigned short hh = f2bf(yv);
            yh[o] = hh;
            yl[o] = f2bf(yv - bf2f(hh));
        }
    }
}

// Fused gate-SiLU + LayerNorm. BF=0: f32 u + f32 gt out; BF=1: split-bf16 u + split-bf16 out.
template<int BF>
__global__ __launch_bounds__(256) void gate_ln_k(const float* __restrict__ G1, const float* __restrict__ G2,
    const float* __restrict__ u, const unsigned short* __restrict__ uh, const unsigned short* __restrict__ ul,
    const float* __restrict__ mf,
    const float* __restrict__ lnw, const float* __restrict__ lnb,
    float* __restrict__ gt, unsigned short* __restrict__ gth, unsigned short* __restrict__ gtl)
{
    int m = blockIdx.x;
    int tid = threadIdx.x;
    __shared__ float buf[1024];
    __shared__ float sb[4][2];
    __shared__ float stats[2];
    float s = 0.f, s2 = 0.f;
    #pragma unroll
    for (int c = tid; c < 1024; c += 256) {
        float g, comb;
        if (c < 512) {
            g = G1[(size_t)m*512 + c];
            if constexpr (BF == 0) comb = u[(size_t)m*512 + c];
            else comb = bf2f(uh[(size_t)m*512 + c]) + bf2f(ul[(size_t)m*512 + c]);
        } else {
            g = G2[(size_t)m*512 + c - 512];
            comb = mf[(size_t)m*512 + c - 512];
        }
        float v = (g / (1.f + expf(-g))) * comb;
        buf[c] = v;
        s += v; s2 += v*v;
    }
    for (int off = 32; off > 0; off >>= 1) { s += __shfl_down(s, off, 64); s2 += __shfl_down(s2, off, 64); }
    int wid = tid >> 6, lane = tid & 63;
    if (lane == 0) { sb[wid][0] = s; sb[wid][1] = s2; }
    __syncthreads();
    if (tid == 0) {
        float S  = sb[0][0]+sb[1][0]+sb[2][0]+sb[3][0];
        float S2 = sb[0][1]+sb[1][1]+sb[2][1]+sb[3][1];
        float mu = S*(1.f/1024.f);
        float var = S2*(1.f/1024.f) - mu*mu;
        stats[0] = mu; stats[1] = rsqrtf(var + EPSF);
    }
    __syncthreads();
    float mu = stats[0], rs = stats[1];
    #pragma unroll
    for (int c = tid; c < 1024; c += 256) {
        float v = (buf[c]-mu)*rs*lnw[c] + lnb[c];
        size_t o = (size_t)m*1024 + c;
        if constexpr (BF == 0) {
            gt[o] = v;
        } else {
            unsigned short hh = f2bf(v);
            gth[o] = hh;
            gtl[o] = f2bf(v - bf2f(hh));
        }
    }
}

// ---------------------------------------------------------------------------
extern "C" void kernel_launch(void* const* d_in, const int* in_sizes, int n_in,
                              void* d_out, int out_size, void* d_ws, size_t ws_size,
                              hipStream_t stream)
{
    (void)in_sizes; (void)n_in; (void)out_size;
    const float* x        = (const float*)d_in[0];
    const float* conv_w   = (const float*)d_in[2];
    const float* conv_b   = (const float*)d_in[3];
    const float* gn_w     = (const float*)d_in[4];
    const float* gn_b     = (const float*)d_in[5];
    const float* in_projw = (const float*)d_in[6];
    const float* mconv_w  = (const float*)d_in[7];
    const float* mconv_b  = (const float*)d_in[8];
    const float* x_projw  = (const float*)d_in[9];
    const float* dt_projw = (const float*)d_in[10];
    const float* dt_projb = (const float*)d_in[11];
    const float* A_log    = (const float*)d_in[12];
    const float* Dp       = (const float*)d_in[13];
    const float* out_projw= (const float*)d_in[14];
    const float* gate_w   = (const float*)d_in[15];
    const float* ln_w     = (const float*)d_in[16];
    const float* ln_b     = (const float*)d_in[17];
    const float* proj_w   = (const float*)d_in[18];
    const unsigned char* msk = (const unsigned char*)d_in[19];
    float* out = (float*)d_out;
    float* ws  = (float*)d_ws;

    const size_t NEL = (size_t)BB*CC*TT;        // 4,194,304
    const size_t NCHW = (size_t)BB*NCH*DINNER;  // 262,144
    float* gsum = ws;
    float* hA   = gsum + NEL;
    float* hB   = hA + NEL;
    float* mf   = hB + NEL;
    float* xz   = mf + NEL;
    float* xc   = xz + (size_t)MROWS*2048;
    float* xdbl = xc + (size_t)MROWS*1024;
    float* dtb  = xdbl + (size_t)MROWS*64;
    float* yb   = dtb + (size_t)MROWS*1024;
    float* red  = yb + (size_t)MROWS*1024;
    float* ch_sd= red + 64;
    // Aliases
    float* ch_h = hA;
    float* hinit= gsum;
    float* G1  = xz;
    float* G2  = xz + NEL;
    float* u   = hB;

    // Path-A: u split lives IN hB (2*NEL ushorts == NEL floats, exact fit);
    // per-layer weight split scratch after ch_sd (4 MB; in_proj is the max).
    unsigned short* uhp = (unsigned short*)hB;
    unsigned short* ulp = uhp + NEL;
    unsigned short* wsc = (unsigned short*)(ch_sd + NCHW);
    const size_t IPL_E = (size_t)2048*512;     // per-layer in_proj elements (1,048,576)
    const size_t OPL_E = (size_t)512*1024;     // per-layer out_proj elements (524,288)
    const size_t GW_E  = (size_t)1024*512;     // gate_w elements (524,288)
    const size_t PW_E  = (size_t)512*1024;     // proj_w elements (524,288)
    unsigned short* iph = wsc;  unsigned short* ipl = wsc + IPL_E;
    unsigned short* oph = wsc;  unsigned short* opl = wsc + OPL_E;
    unsigned short* gwh = wsc;  unsigned short* gwl = wsc + GW_E;
    unsigned short* pwh = wsc;  unsigned short* pwl = wsc + PW_E;
    size_t req = (size_t)((char*)(wsc + 2*IPL_E) - (char*)ws);   // ~242.2 MB
    const bool pathA = (ws_size >= req);
    // In-place bf16 aliases (dead f32 regions)
    unsigned short* ybh = (unsigned short*)yb;  unsigned short* ybl = ybh + (size_t)MROWS*1024;
    unsigned short* mfh = (unsigned short*)hA;  unsigned short* mfl = mfh + NEL;
    unsigned short* gth = (unsigned short*)yb;  unsigned short* gtl = gth + (size_t)MROWS*1024;
    float* gt2 = pathA ? xc : yb;   // proj output; path B keeps r6 placement (gt=xc, gt2=yb)
    float* gt  = xc;

    // ---- front conv/GN/SiLU stack (ping-pong hB/hA) ----
    const float* cur_in = x;
    float* pp[2] = {hB, hA};
    for (int i = 0; i < 4; ++i) {
        float* co = pp[i & 1];
        front_conv_k<<<16384, 256, 0, stream>>>(cur_in, conv_w + (size_t)i*CC*12, conv_b + i*CC, co);
        hipMemsetAsync(red, 0, 32*sizeof(float), stream);
        gn_stats_k<<<256, 256, 0, stream>>>(co, red);
        if (i == 0) gn_apply_k<true ><<<16384, 256, 0, stream>>>(co, gsum, red, gn_w + i*CC, gn_b + i*CC);
        else        gn_apply_k<false><<<16384, 256, 0, stream>>>(co, gsum, red, gn_w + i*CC, gn_b + i*CC);
        cur_in = co;
    }

    // u = gsum^T (gsum dead afterwards -> hinit). Path A emits split bf16 into hB.
    if (pathA)
        transpose_split_k<<<dim3(64,16,4), dim3(32,8), 0, stream>>>(gsum, uhp, ulp);
    else
        transpose_k<false><<<dim3(64,16,4), dim3(32,8), 0, stream>>>(gsum, u, CC, TT, nullptr);

    // ---- 4 mamba blocks ----
    for (int i = 0; i < 4; ++i) {
        if (pathA) {
            split_bf16_k<<<512, 256, 0, stream>>>(in_projw + (size_t)i*IPL_E, iph, ipl, (int)(IPL_E/8));
            gemm_bf16s_k<128,false><<<dim3(16,64), 256, 0, stream>>>(uhp, ulp, iph, ipl, xz, 2048, 512);
        } else {
            gemm_mfma_k<false><<<dim3(16,64), 256, 0, stream>>>(u, in_projw + (size_t)i*2048*512, xz, 2048, 512);
        }
        mamba_conv_k<<<32768, 256, 0, stream>>>(xz, mconv_w + (size_t)i*DINNER*4, mconv_b + i*DINNER, xc);
        gemm_k<0,false><<<dim3(1,128), 256, 0, stream>>>(xc, 1024, x_projw + (size_t)i*64*1024, xdbl, 64, 1024, nullptr);
        gemm_k<1,false><<<dim3(16,128), 256, 0, stream>>>(xdbl, 64, dt_projw + (size_t)i*1024*32, dtb, 1024, 32, dt_projb + i*1024);
        scan_p1_k<<<NCHW/256, 256, 0, stream>>>(dtb, xc, xdbl, A_log + (size_t)i*16384, ch_h, ch_sd);
        scan_p2_k<<<256, 256, 0, stream>>>(A_log + (size_t)i*16384, ch_h, ch_sd, hinit);
        if (pathA) {
            scan_p3_k<1><<<NCHW/256, 256, 0, stream>>>(dtb, xc, xdbl, A_log + (size_t)i*16384, hinit, xz,
                                                       Dp + i*DINNER, nullptr, ybh, ybl);
            split_bf16_k<<<256, 256, 0, stream>>>(out_projw + (size_t)i*OPL_E, oph, opl, (int)(OPL_E/8));
            if (i == 0) gemm_bf16s_k<64,false><<<dim3(8,64), 256, 0, stream>>>(ybh, ybl, oph, opl, mf, 512, 1024);
            else        gemm_bf16s_k<64,true ><<<dim3(8,64), 256, 0, stream>>>(ybh, ybl, oph, opl, mf, 512, 1024);
        } else {
            scan_p3_k<0><<<NCHW/256, 256, 0, stream>>>(dtb, xc, xdbl, A_log + (size_t)i*16384, hinit, xz,
                                                       Dp + i*DINNER, yb, nullptr, nullptr);
            if (i == 0) gemm_mfma_k<false><<<dim3(4,64), 256, 0, stream>>>(yb, out_projw + (size_t)i*512*1024, mf, 512, 1024);
            else        gemm_mfma_k<true ><<<dim3(4,64), 256, 0, stream>>>(yb, out_projw + (size_t)i*512*1024, mf, 512, 1024);
        }
    }

    // ---- gate conv + LN + proj + transpose/mask ----
    if (pathA) {
        split_bf16_k<<<2048, 256, 0, stream>>>(mf, mfh, mfl, (int)(NEL/8));       // hA free after loop
        split_bf16_k<<<256, 256, 0, stream>>>(gate_w, gwh, gwl, (int)(GW_E/8));   // scratch free (ipw/opw dead)
        gemm_bf16s_k<64,false><<<dim3(8,64), 256, 0, stream>>>(uhp, ulp, gwh, gwl, G1, 512, 512);
        gemm_bf16s_k<64,false><<<dim3(8,64), 256, 0, stream>>>(mfh, mfl, gwh + (size_t)512*512, gwl + (size_t)512*512, G2, 512, 512);
        gate_ln_k<1><<<8192, 256, 0, stream>>>(G1, G2, nullptr, uhp, ulp, mf, ln_w, ln_b, nullptr, gth, gtl);
        split_bf16_k<<<256, 256, 0, stream>>>(proj_w, pwh, pwl, (int)(PW_E/8));   // overwrites gate split (dead)
        gemm_bf16s_k<64,false><<<dim3(8,64), 256, 0, stream>>>(gth, gtl, pwh, pwl, gt2, 512, 1024);
    } else {
        gemm_mfma_k<false><<<dim3(4,64), 256, 0, stream>>>(u,  gate_w,           G1, 512, 512);
        gemm_mfma_k<false><<<dim3(4,64), 256, 0, stream>>>(mf, gate_w + 512*512, G2, 512, 512);
        gate_ln_k<0><<<8192, 256, 0, stream>>>(G1, G2, u, nullptr, nullptr, mf, ln_w, ln_b, gt, nullptr, nullptr);
        gemm_mfma_k<false><<<dim3(4,64), 256, 0, stream>>>(gt, proj_w, gt2, 512, 1024);
    }
    transpose_k<true><<<dim3(16,64,4), dim3(32,8), 0, stream>>>(gt2, out, TT, CC, msk);
}